// Round 17
// baseline (265.224 us; speedup 1.0000x reference)
//
#include <hip/hip_runtime.h>
#include <math.h>

#define BDIM 256
constexpr int BB = 4, Cc = 128, Hh = 128, Wd = 128, HW = Hh * Wd;
constexpr float EPSv = 1e-5f;

typedef __attribute__((ext_vector_type(8))) short short8v;
typedef __attribute__((ext_vector_type(4))) float floatx4;
typedef __attribute__((ext_vector_type(2))) float float2v;

#define MFMA16(a, b, c) __builtin_amdgcn_mfma_f32_16x16x32_bf16((a), (b), (c), 0, 0, 0)

__device__ __forceinline__ float sigmoidf_(float v) { return 1.f / (1.f + __expf(-v)); }

__device__ __forceinline__ unsigned short f2bf(float f) {
    union { float f; unsigned u; } v; v.f = f;
    unsigned r = v.u + 0x7FFFu + ((v.u >> 16) & 1u);
    return (unsigned short)(r >> 16);
}
__device__ __forceinline__ unsigned cvtpk(float a, float b) {
    unsigned r;
    asm("v_cvt_pk_bf16_f32 %0, %1, %2" : "=v"(r) : "v"(a), "v"(b));
    return r;
}
__device__ __forceinline__ float bfu(unsigned short u) { union { unsigned u; float f; } v; v.u = ((unsigned)u) << 16; return v.f; }
__device__ __forceinline__ float2v unpk2(unsigned u) {
    union { unsigned x[2]; float2v f; } v;
    v.x[0] = u << 16;
    v.x[1] = u & 0xFFFF0000u;
    return v.f;
}

// LDS-only barrier: does NOT drain vmcnt (in-flight prefetch survives).
__device__ __forceinline__ void barrier_lgkm() {
    asm volatile("s_waitcnt lgkmcnt(0)" ::: "memory");
    __builtin_amdgcn_s_barrier();
}

// async global->LDS, 16B per lane; lds dest = uniform base + lane*16
__device__ __forceinline__ void gload16(const void* g, void* l) {
    __builtin_amdgcn_global_load_lds(
        (const __attribute__((address_space(1))) unsigned int*)g,
        (__attribute__((address_space(3))) unsigned int*)l, 16, 0, 0);
}

// ---- all weight repacks fused: wpkAF(attn|feat), wpkO, wpkOM, bom ----
__global__ void repack_all_k(const float* __restrict__ w_attn, const float* __restrict__ w_feat,
                             const float* __restrict__ w_org, const float* __restrict__ w_off,
                             const float* __restrict__ w_mask, const float* __restrict__ b_off,
                             const float* __restrict__ b_mask,
                             unsigned short* __restrict__ wpkAF, unsigned short* __restrict__ wpkO,
                             unsigned short* __restrict__ wpkOM, float* __restrict__ bom) {
    int idx = blockIdx.x * BDIM + threadIdx.x;
    const int TOT = 26 * 18432;
    if (idx < TOT) {
        int seg = idx / 18432, rem = idx % 18432;
        int i = rem & 7, lane = (rem >> 3) & 63, tap = (rem >> 9) % 9, chunk = rem / (9 * 512);
        int lco = lane & 15;
        int ci = chunk * 32 + (lane >> 4) * 8 + i;
        float v = 0.f;
        unsigned short* dst;
        int didx;
        if (seg < 16) {
            int cot = seg & 7;
            const float* w = (seg < 8) ? w_attn : w_feat;
            int co = cot * 16 + lco;
            v = w[((size_t)co * Cc + ci) * 9 + tap];
            dst = wpkAF; didx = idx;
        } else if (seg < 24) {
            int co = (seg - 16) * 16 + lco;
            v = w_org[((size_t)co * Cc + ci) * 9 + tap];
            dst = wpkO; didx = idx - 16 * 18432;
        } else {
            int co = (seg - 24) * 16 + lco;
            if (co < 18)      v = w_off[((size_t)co * Cc + ci) * 9 + tap];
            else if (co < 27) v = w_mask[((size_t)(co - 18) * Cc + ci) * 9 + tap];
            dst = wpkOM; didx = idx - 24 * 18432;
        }
        dst[didx] = f2bf(v);
    } else if (idx < TOT + 32) {
        int j = idx - TOT;
        bom[j] = (j < 18) ? b_off[j] : (j < 27 ? b_mask[j - 18] : 0.f);
    }
}

// ---- x (NCHW f32) -> dst (NHWC bf16, guarded base) ----
__global__ __launch_bounds__(256) void tobf_k(const float* __restrict__ x,
                                              unsigned short* __restrict__ dst) {
    const int h = blockIdx.x, b = blockIdx.y;
    const int t = threadIdx.x;
    __shared__ unsigned short lt[16][128];
    const int ciq = t >> 4, wg = t & 15;
    const int w = t >> 1, half = t & 1;
    for (int s = 0; s < 8; s++) {
        const float* p = x + ((size_t)(b * 128 + s * 16 + ciq) * HW + h * 128 + wg * 8);
        float4 a = *(const float4*)p;
        float4 c = *(const float4*)(p + 4);
        *(uint4*)&lt[ciq][wg * 8] =
            make_uint4(cvtpk(a.x, a.y), cvtpk(a.z, a.w), cvtpk(c.x, c.y), cvtpk(c.z, c.w));
        __syncthreads();
        unsigned r[4];
#pragma unroll
        for (int k = 0; k < 4; k++) {
            unsigned lo = lt[half * 8 + 2 * k][w];
            unsigned hi = lt[half * 8 + 2 * k + 1][w];
            r[k] = lo | (hi << 16);
        }
        *(uint4*)(dst + ((size_t)b * HW + h * 128 + w) * 128 + s * 16 + half * 8) =
            make_uint4(r[0], r[1], r[2], r[3]);
        __syncthreads();
    }
}

// ---- MFMA implicit-GEMM conv3x3 (pad=1), global_load_lds + afr ping-pong,
//      (rowr,dx)-loop B-fragment reuse ----
template <int COTPB, int WCO, bool SWZ>
__global__ __launch_bounds__(256, 2) void conv3_k(
    const unsigned short* __restrict__ src, const unsigned short* __restrict__ wpk,
    const float* __restrict__ biasA, const float* __restrict__ biasB,
    int bsplit, int sigsplit,
    float* __restrict__ out, int ldc, int ch0) {
    constexpr int ROWS = 2;
    constexpr int WPX = 4 / WCO;
    constexpr int PXW = 128 / WPX;
    constexpr int PS = PXW / 16;
    constexpr int HB = 128 / ROWS;

    const int t = threadIdx.x;
    const int lane = t & 63, llo = t & 15, lhi = (t >> 4) & 3;
    const int widu = __builtin_amdgcn_readfirstlane(t >> 6);
    const int wr = widu / WPX, wc = widu % WPX;

    int cbi, h0, b;
    if (SWZ) {
        int n = blockIdx.x;
        int xcd = n & 7, j = n >> 3;
        int g = (j >> 2) * 8 + xcd;
        cbi = j & 3;
        h0 = (g % HB) * ROWS;
        b = g / HB;
    } else {
        cbi = 0;
        h0 = ((int)blockIdx.x % HB) * ROWS;
        b = (int)blockIdx.x / HB;
    }
    const int cotbase = cbi * COTPB + wr * 2;

    __shared__ unsigned short xs[2][4][4][128][8];  // 64 KB

    floatx4 acc[2][ROWS][PS];
#pragma unroll
    for (int c = 0; c < 2; c++)
#pragma unroll
        for (int row = 0; row < ROWS; row++)
#pragma unroll
            for (int ps = 0; ps < PS; ps++) acc[c][row][ps] = (floatx4){0.f, 0.f, 0.f, 0.f};

    const unsigned short* srcb = src + ((size_t)b * HW + (size_t)(h0 - 1) * 128) * 128;

    auto stage = [&](int chunk, int buf) {
        const unsigned short* sb = srcb + chunk * 32 + widu * 8;
        unsigned short* db = &xs[buf][widu][0][0][0];
#pragma unroll
        for (int i = 0; i < 8; i++) {
            const unsigned short* g = sb + (size_t)(i * 64 + lane) * 128;
            gload16(g, db + i * 512);
        }
    };

    short8v afrA[9][2], afrB[9][2];
    auto loadafr = [&](int chunk, short8v (*dst)[2]) {
#pragma unroll
        for (int tap = 0; tap < 9; tap++)
#pragma unroll
            for (int c = 0; c < 2; c++)
                dst[tap][c] = *(const short8v*)(wpk +
                    ((((size_t)(cotbase + c) * 4 + chunk) * 9 + tap) * 64 + lane) * 8);
    };

    stage(0, 0);
    loadafr(0, afrA);
    __syncthreads();

    const int wcb = wc * PXW;
#pragma unroll
    for (int chunk = 0; chunk < 4; ++chunk) {
        const int buf = chunk & 1;
        if (chunk < 3) {
            stage(chunk + 1, buf ^ 1);
            loadafr(chunk + 1, (chunk & 1) ? afrA : afrB);
        }
        short8v (*cur)[2] = (chunk & 1) ? afrB : afrA;
#pragma unroll
        for (int rowr = 0; rowr < ROWS + 2; ++rowr) {
            const int hh = h0 - 1 + rowr;
            if ((unsigned)hh < 128u) {
#pragma unroll
                for (int dx = 0; dx < 3; ++dx) {
#pragma unroll
                    for (int ps = 0; ps < PS; ps++) {
                        int colr = wcb + ps * 16 + llo + dx - 1;
                        int colc = min(max(colr, 0), 127);
                        short8v bfv = *(const short8v*)&xs[buf][lhi][rowr][colc][0];
                        if (colr != colc) bfv = (short8v)(short)0;
#pragma unroll
                        for (int row = 0; row < ROWS; ++row) {
                            const int r = rowr - row;
                            if (r >= 0 && r < 3) {
                                const int tap = r * 3 + dx;
#pragma unroll
                                for (int c = 0; c < 2; c++)
                                    acc[c][row][ps] = MFMA16(cur[tap][c], bfv, acc[c][row][ps]);
                            }
                        }
                    }
                }
            }
        }
        __syncthreads();
    }

    const int cbase = cbi * (COTPB * 16);
    const float* bp = (cbase < bsplit) ? biasA : biasB;
    const int bshift = (cbase < bsplit) ? 0 : bsplit;
    const bool dosig = cbase < sigsplit;
#pragma unroll
    for (int c = 0; c < 2; c++)
#pragma unroll
        for (int row = 0; row < ROWS; row++)
#pragma unroll
            for (int ps = 0; ps < PS; ps++)
#pragma unroll
                for (int reg = 0; reg < 4; reg++) {
                    int co = cbase + (wr * 2 + c) * 16 + lhi * 4 + reg;
                    int px = wc * PXW + ps * 16 + llo;
                    float v = acc[c][row][ps][reg] + bp[co - bshift];
                    if (dosig) v = sigmoidf_(v);
                    out[((size_t)b * ldc + ch0 + co) * HW + (h0 + row) * Wd + px] = v;
                }
}

// ---- instance-norm stats ----
__global__ __launch_bounds__(256) void inorm_stats_k(const float* __restrict__ src,
                                                     float* __restrict__ mu, float* __restrict__ rsig,
                                                     int chTot, int ch0) {
    const int bc = blockIdx.x;
    const int b = bc >> 7, c = bc & 127;
    const float4* p = (const float4*)(src + ((size_t)b * chTot + ch0 + c) * HW);
    float s = 0.f, s2 = 0.f;
    for (int i = threadIdx.x; i < HW / 4; i += BDIM) {
        float4 v = p[i];
        s += v.x + v.y + v.z + v.w;
        s2 += v.x * v.x + v.y * v.y + v.z * v.z + v.w * v.w;
    }
    __shared__ float ss[BDIM], sq[BDIM];
    int t = threadIdx.x;
    ss[t] = s; sq[t] = s2;
    __syncthreads();
    for (int off = BDIM / 2; off > 0; off >>= 1) {
        if (t < off) { ss[t] += ss[t + off]; sq[t] += sq[t + off]; }
        __syncthreads();
    }
    if (t == 0) {
        float m = ss[0] / HW;
        float var = sq[0] / HW - m * m;
        mu[bc] = m;
        rsig[bc] = rsqrtf(var + EPSv);
    }
}

// ---- xa = lrelu(norm(featRaw)) * attn -> xabf (NHWC bf16, guarded base) ----
__global__ __launch_bounds__(256) void xattned2_k(const float* __restrict__ rawAF,
                                                  const float* __restrict__ mu,
                                                  const float* __restrict__ rsig,
                                                  unsigned short* __restrict__ xabfG) {
    const int seg = blockIdx.x, h = blockIdx.y, b = blockIdx.z;
    const int t = threadIdx.x;
    __shared__ unsigned short la[64][128];
    const int px4 = t & 15, cl = t >> 4;
#pragma unroll
    for (int p = 0; p < 8; p++) {
        int c = p * 16 + cl;
        int plane = b * 128 + c;
        size_t pixo = (size_t)h * Wd + seg * 64 + px4 * 4;
        float4 a = *(const float4*)(rawAF + ((size_t)b * 256 + c) * HW + pixo);
        float4 f = *(const float4*)(rawAF + ((size_t)b * 256 + 128 + c) * HW + pixo);
        float m = mu[plane], rs = rsig[plane];
        float vs[4];
        float v;
        v = (f.x - m) * rs; v = v > 0.f ? v : 0.2f * v; vs[0] = v * a.x;
        v = (f.y - m) * rs; v = v > 0.f ? v : 0.2f * v; vs[1] = v * a.y;
        v = (f.z - m) * rs; v = v > 0.f ? v : 0.2f * v; vs[2] = v * a.z;
        v = (f.w - m) * rs; v = v > 0.f ? v : 0.2f * v; vs[3] = v * a.w;
#pragma unroll
        for (int j = 0; j < 4; j++) la[px4 * 4 + j][c] = f2bf(vs[j]);
    }
    __syncthreads();
    const int px = t >> 2, part = t & 3;
    const uint4* lp = (const uint4*)&la[px][part * 32];
    unsigned short* dp = xabfG + ((size_t)b * HW + h * 128 + seg * 64 + px) * 128 + part * 32;
    uint4 v0 = lp[0], v1 = lp[1], v2 = lp[2], v3 = lp[3];
    *(uint4*)dp = v0;
    *(uint4*)(dp + 8) = v1;
    *(uint4*)(dp + 16) = v2;
    *(uint4*)(dp + 24) = v3;
}

// ---- deformable conv, 32-px blocks (r13 pipeline). (256,6): VGPR demand measured 64 < cap 85,
//      LDS 26.1KB allows 6 blocks/CU -> raise resident waves 16->24 per CU. ----
__global__ __launch_bounds__(256, 6) void deform_mfma_k(
    const unsigned short* __restrict__ xabfG, const float* __restrict__ om,
    const unsigned short* __restrict__ wpkO, const float* __restrict__ b_org,
    float* __restrict__ out, int ldc, int ch0) {
    const int seg = blockIdx.x, h = blockIdx.y, b = blockIdx.z;
    const int t = threadIdx.x;
    const int lane = t & 63, llo = t & 15, lhi = (t >> 4) & 3;
    const int wid = t >> 6;
    const int cb = seg * 32;

    __shared__ unsigned short sv[4][9][32][8];
    __shared__ unsigned xt[8 * 6 * 40];

    int prA[2][4];
    float prW[2][4];
    int prT0[2], prOff[2];
    bool prV[2], prOK[2];

    const float* omb = om + (size_t)b * 32 * HW;
#pragma unroll
    for (int u = 0; u < 2; u++) {
        bool valid;
        int pc;
        if (u == 0) { valid = true; pc = t; }
        else { valid = t < 32; pc = 256 + (t & 31); }
        int tap = pc >> 5, pxl = pc & 31;
        int ww = cb + pxl;
        int pix = h * Wd + ww;
        float dy = omb[(size_t)(2 * tap) * HW + pix];
        float dxv = omb[(size_t)(2 * tap + 1) * HW + pix];
        float msk = sigmoidf_(omb[(size_t)(18 + tap) * HW + pix]);
        float yy = dy + (float)(h + tap / 3 - 1);
        float xx = dxv + (float)(ww + tap % 3 - 1);
        float y0f = floorf(yy), x0f = floorf(xx);
        float wy = yy - y0f, wx = xx - x0f;
        int y0 = (int)y0f, x0 = (int)x0f;
#pragma unroll
        for (int c2 = 0; c2 < 4; c2++) {
            int ddy = c2 >> 1, ddx = c2 & 1;
            int yi = y0 + ddy, xi = x0 + ddx;
            bool vc = (yi >= 0) && (yi < Hh) && (xi >= 0) && (xi < Wd);
            int yc = min(max(yi, 0), Hh - 1), xc = min(max(xi, 0), Wd - 1);
            float wt = (ddy ? wy : 1.f - wy) * (ddx ? wx : 1.f - wx);
            prA[u][c2] = yc * Wd + xc;
            prW[u][c2] = vc ? wt * msk : 0.f;
        }
        int ty0 = y0 - (h - 2);
        int tx0 = x0 - (cb - 2);
        prOK[u] = ((unsigned)ty0 <= 4u) && ((unsigned)tx0 <= 38u);
        prT0[u] = ty0 * 40 + tx0;
        prOff[u] = tap * 32 + pxl;
        prV[u] = valid;
    }

    floatx4 acc[2][2];
#pragma unroll
    for (int c = 0; c < 2; c++)
#pragma unroll
        for (int ps = 0; ps < 2; ps++) acc[c][ps] = (floatx4){0.f, 0.f, 0.f, 0.f};

    const unsigned short* xab = xabfG + (size_t)b * HW * 128;
    unsigned short* svf = &sv[0][0][0][0];

    uint4 U[2];

    auto issue_stage = [&](int nc) {
        const int cbase = nc * 16;
#pragma unroll
        for (int it = 0; it < 2; it++) {
            int task = t + it * 256;
            if (task < 480) {
                int col = task % 40;
                int rg = task / 40;
                int row = rg % 6, grp = rg / 6;
                int r = h - 2 + row, cX = cb - 2 + col;
                int rc = min(max(r, 0), Hh - 1), cc = min(max(cX, 0), Wd - 1);
                U[it] = *(const uint4*)(xab + ((size_t)rc * 128 + cc) * 128 + cbase + grp * 8);
            }
        }
    };

    issue_stage(0);

    for (int chunk = 0; chunk < 4; ++chunk) {
#pragma unroll
        for (int half = 0; half < 2; ++half) {
            barrier_lgkm();
#pragma unroll
            for (int it = 0; it < 2; it++) {
                int task = t + it * 256;
                if (task < 480) {
                    int col = task % 40;
                    int rg = task / 40;
                    int row = rg % 6, grp = rg / 6;
                    int cell = row * 40 + col;
                    xt[(grp * 4 + 0) * 240 + cell] = U[it].x;
                    xt[(grp * 4 + 1) * 240 + cell] = U[it].y;
                    xt[(grp * 4 + 2) * 240 + cell] = U[it].z;
                    xt[(grp * 4 + 3) * 240 + cell] = U[it].w;
                }
            }
            int nc = chunk * 2 + half + 1;
            if (nc < 8) issue_stage(nc);
            barrier_lgkm();
#pragma unroll
            for (int u = 0; u < 2; u++) {
                if (!prV[u]) continue;
                const float w0 = prW[u][0], w1 = prW[u][1], w2 = prW[u][2], w3 = prW[u][3];
                if (prOK[u]) {
                    const unsigned* xp = xt + prT0[u];
                    unsigned q[8];
#pragma unroll
                    for (int c2 = 0; c2 < 8; c2++) {
                        unsigned c00 = xp[0], c01 = xp[1];
                        unsigned c10 = xp[40], c11 = xp[41];
                        float2v s = unpk2(c00) * w0 + unpk2(c01) * w1
                                  + unpk2(c10) * w2 + unpk2(c11) * w3;
                        q[c2] = cvtpk(s[0], s[1]);
                        xp += 240;
                    }
                    *(uint4*)(svf + ((size_t)((half * 2 + 0) * 288 + prOff[u]) << 3)) =
                        make_uint4(q[0], q[1], q[2], q[3]);
                    *(uint4*)(svf + ((size_t)((half * 2 + 1) * 288 + prOff[u]) << 3)) =
                        make_uint4(q[4], q[5], q[6], q[7]);
                } else {
                    const int a0 = prA[u][0], a1 = prA[u][1], a2 = prA[u][2], a3 = prA[u][3];
                    const int cch = chunk * 32 + half * 16;
#pragma unroll
                    for (int cg2 = 0; cg2 < 2; cg2++) {
                        unsigned q[4];
#pragma unroll
                        for (int pair = 0; pair < 4; pair++) {
                            int co8 = cch + cg2 * 8 + 2 * pair;
                            unsigned c0 = *(const unsigned*)(xab + (size_t)a0 * 128 + co8);
                            unsigned c1 = *(const unsigned*)(xab + (size_t)a1 * 128 + co8);
                            unsigned c2v = *(const unsigned*)(xab + (size_t)a2 * 128 + co8);
                            unsigned c3 = *(const unsigned*)(xab + (size_t)a3 * 128 + co8);
                            float2v s = unpk2(c0) * w0 + unpk2(c1) * w1
                                      + unpk2(c2v) * w2 + unpk2(c3) * w3;
                            q[pair] = cvtpk(s[0], s[1]);
                        }
                        *(uint4*)(svf + ((size_t)((half * 2 + cg2) * 288 + prOff[u]) << 3)) =
                            make_uint4(q[0], q[1], q[2], q[3]);
                    }
                }
            }
        }
        barrier_lgkm();
#pragma unroll
        for (int tap = 0; tap < 9; ++tap) {
            short8v af[2];
#pragma unroll
            for (int c = 0; c < 2; c++) {
                int cot = wid * 2 + c;
                af[c] = *(const short8v*)(wpkO + ((((size_t)cot * 4 + chunk) * 9 + tap) * 64 + lane) * 8);
            }
            short8v bf[2];
#pragma unroll
            for (int ps = 0; ps < 2; ps++)
                bf[ps] = *(const short8v*)&sv[lhi][tap][ps * 16 + llo][0];
#pragma unroll
            for (int c = 0; c < 2; c++)
#pragma unroll
                for (int ps = 0; ps < 2; ps++)
                    acc[c][ps] = MFMA16(af[c], bf[ps], acc[c][ps]);
        }
    }

#pragma unroll
    for (int c = 0; c < 2; c++)
#pragma unroll
        for (int ps = 0; ps < 2; ps++)
#pragma unroll
            for (int reg = 0; reg < 4; reg++) {
                int co = (wid * 2 + c) * 16 + lhi * 4 + reg;
                int px = cb + ps * 16 + llo;
                out[((size_t)b * ldc + ch0 + co) * HW + h * Wd + px] = acc[c][ps][reg] + b_org[co];
            }
}

// ---- out = xa + lrelu(norm(dconv)) * (1 - attn) ; xa from xabf via LDS ----
__global__ __launch_bounds__(256) void final2_k(const float* __restrict__ rawAF,
                                                const unsigned short* __restrict__ xabfG,
                                                const float* __restrict__ mu,
                                                const float* __restrict__ rsig,
                                                float* __restrict__ outp) {
    const int seg = blockIdx.x, h = blockIdx.y, b = blockIdx.z;
    const int t = threadIdx.x;
    __shared__ unsigned short la[64][128];
    {
        const int px = t >> 2, part = t & 3;
        const unsigned short* sp = xabfG + ((size_t)b * HW + h * 128 + seg * 64 + px) * 128 + part * 32;
        uint4* lp = (uint4*)&la[px][part * 32];
        lp[0] = *(const uint4*)sp;
        lp[1] = *(const uint4*)(sp + 8);
        lp[2] = *(const uint4*)(sp + 16);
        lp[3] = *(const uint4*)(sp + 24);
    }
    __syncthreads();
    const int px4 = t & 15, cl = t >> 4;
#pragma unroll
    for (int p = 0; p < 8; p++) {
        int c = p * 16 + cl;
        int plane = b * 128 + c;
        size_t pixo = (size_t)h * Wd + seg * 64 + px4 * 4;
        float4 a = *(const float4*)(rawAF + ((size_t)b * 256 + c) * HW + pixo);
        float4 d = *(const float4*)(rawAF + ((size_t)b * 256 + 128 + c) * HW + pixo);
        float m = mu[plane], rs = rsig[plane];
        float4 o;
        float v;
        v = (d.x - m) * rs; v = v > 0.f ? v : 0.2f * v; o.x = bfu(la[px4 * 4 + 0][c]) + v * (1.f - a.x);
        v = (d.y - m) * rs; v = v > 0.f ? v : 0.2f * v; o.y = bfu(la[px4 * 4 + 1][c]) + v * (1.f - a.y);
        v = (d.z - m) * rs; v = v > 0.f ? v : 0.2f * v; o.z = bfu(la[px4 * 4 + 2][c]) + v * (1.f - a.z);
        v = (d.w - m) * rs; v = v > 0.f ? v : 0.2f * v; o.w = bfu(la[px4 * 4 + 3][c]) + v * (1.f - a.w);
        *(float4*)(outp + (size_t)plane * HW + pixo) = o;
    }
}

extern "C" void kernel_launch(void* const* d_in, const int* in_sizes, int n_in,
                              void* d_out, int out_size, void* d_ws, size_t ws_size,
                              hipStream_t stream) {
    const float* x      = (const float*)d_in[0];
    const float* w_attn = (const float*)d_in[1];
    const float* b_attn = (const float*)d_in[2];
    const float* w_feat = (const float*)d_in[3];
    const float* b_feat = (const float*)d_in[4];
    const float* w_org  = (const float*)d_in[5];
    const float* b_org  = (const float*)d_in[6];
    const float* w_off  = (const float*)d_in[7];
    const float* b_off  = (const float*)d_in[8];
    const float* w_mask = (const float*)d_in[9];
    const float* b_mask = (const float*)d_in[10];
    float* out = (float*)d_out;
    (void)in_sizes; (void)n_in; (void)out_size; (void)ws_size;

    float* ws = (float*)d_ws;
    float* rawAF = ws;
    unsigned short* regionA = (unsigned short*)(ws + (size_t)BB * 256 * HW);
    unsigned short* xbfG  = regionA + 16384;             // aliased: x-bf16 then xa-bf16
    const size_t bfElems = (size_t)BB * HW * 128;
    float* offm = (float*)(regionA + 2 * 16384 + bfElems);
    float* tail = offm + (size_t)BB * 32 * HW;
    unsigned short* wpkAF = (unsigned short*)tail;
    unsigned short* wpkO  = wpkAF + (size_t)16 * 18432;
    unsigned short* wpkOM = wpkO + (size_t)8 * 18432;
    float* bOM = (float*)(wpkOM + (size_t)2 * 18432);
    float* mu1 = bOM + 32;
    float* rs1 = mu1 + 512;
    float* mu2 = rs1 + 512;
    float* rs2 = mu2 + 512;

    repack_all_k<<<(26 * 18432 + 32 + BDIM - 1) / BDIM, BDIM, 0, stream>>>(
        w_attn, w_feat, w_org, w_off, w_mask, b_off, b_mask, wpkAF, wpkO, wpkOM, bOM);

    tobf_k<<<dim3(Hh, BB), BDIM, 0, stream>>>(x, xbfG);

    conv3_k<4, 2, true><<<1024, BDIM, 0, stream>>>(
        xbfG, wpkAF, b_attn, b_feat, 128, 128, rawAF, 256, 0);

    inorm_stats_k<<<BB * Cc, BDIM, 0, stream>>>(rawAF, mu1, rs1, 256, 128);

    xattned2_k<<<dim3(2, Hh, BB), BDIM, 0, stream>>>(rawAF, mu1, rs1, xbfG);

    conv3_k<2, 1, false><<<256, BDIM, 0, stream>>>(
        xbfG, wpkOM, bOM, bOM, 32, 0, offm, 32, 0);

    deform_mfma_k<<<dim3(4, Hh, BB), BDIM, 0, stream>>>(
        xbfG, offm, wpkO, b_org, rawAF, 256, 128);

    inorm_stats_k<<<BB * Cc, BDIM, 0, stream>>>(rawAF, mu2, rs2, 256, 128);

    final2_k<<<dim3(2, Hh, BB), BDIM, 0, stream>>>(rawAF, xbfG, mu2, rs2, out);
}

// Round 18
// 184.313 us; speedup vs baseline: 1.4390x; 1.4390x over previous
//
#include <hip/hip_runtime.h>
#include <math.h>

#define BDIM 256
constexpr int BB = 4, Cc = 128, Hh = 128, Wd = 128, HW = Hh * Wd;
constexpr float EPSv = 1e-5f;

typedef __attribute__((ext_vector_type(8))) short short8v;
typedef __attribute__((ext_vector_type(4))) float floatx4;
typedef __attribute__((ext_vector_type(2))) float float2v;

#define MFMA16(a, b, c) __builtin_amdgcn_mfma_f32_16x16x32_bf16((a), (b), (c), 0, 0, 0)

__device__ __forceinline__ float sigmoidf_(float v) { return 1.f / (1.f + __expf(-v)); }

__device__ __forceinline__ unsigned short f2bf(float f) {
    union { float f; unsigned u; } v; v.f = f;
    unsigned r = v.u + 0x7FFFu + ((v.u >> 16) & 1u);
    return (unsigned short)(r >> 16);
}
__device__ __forceinline__ unsigned cvtpk(float a, float b) {
    unsigned r;
    asm("v_cvt_pk_bf16_f32 %0, %1, %2" : "=v"(r) : "v"(a), "v"(b));
    return r;
}
__device__ __forceinline__ float bfu(unsigned short u) { union { unsigned u; float f; } v; v.u = ((unsigned)u) << 16; return v.f; }
__device__ __forceinline__ float2v unpk2(unsigned u) {
    union { unsigned x[2]; float2v f; } v;
    v.x[0] = u << 16;
    v.x[1] = u & 0xFFFF0000u;
    return v.f;
}

// LDS-only barrier: does NOT drain vmcnt (in-flight prefetch survives).
__device__ __forceinline__ void barrier_lgkm() {
    asm volatile("s_waitcnt lgkmcnt(0)" ::: "memory");
    __builtin_amdgcn_s_barrier();
}

// async global->LDS, 16B per lane; lds dest = uniform base + lane*16
__device__ __forceinline__ void gload16(const void* g, void* l) {
    __builtin_amdgcn_global_load_lds(
        (const __attribute__((address_space(1))) unsigned int*)g,
        (__attribute__((address_space(3))) unsigned int*)l, 16, 0, 0);
}

// ---- all weight repacks fused: wpkAF(attn|feat), wpkO, wpkOM, bom ----
__global__ void repack_all_k(const float* __restrict__ w_attn, const float* __restrict__ w_feat,
                             const float* __restrict__ w_org, const float* __restrict__ w_off,
                             const float* __restrict__ w_mask, const float* __restrict__ b_off,
                             const float* __restrict__ b_mask,
                             unsigned short* __restrict__ wpkAF, unsigned short* __restrict__ wpkO,
                             unsigned short* __restrict__ wpkOM, float* __restrict__ bom) {
    int idx = blockIdx.x * BDIM + threadIdx.x;
    const int TOT = 26 * 18432;
    if (idx < TOT) {
        int seg = idx / 18432, rem = idx % 18432;
        int i = rem & 7, lane = (rem >> 3) & 63, tap = (rem >> 9) % 9, chunk = rem / (9 * 512);
        int lco = lane & 15;
        int ci = chunk * 32 + (lane >> 4) * 8 + i;
        float v = 0.f;
        unsigned short* dst;
        int didx;
        if (seg < 16) {
            int cot = seg & 7;
            const float* w = (seg < 8) ? w_attn : w_feat;
            int co = cot * 16 + lco;
            v = w[((size_t)co * Cc + ci) * 9 + tap];
            dst = wpkAF; didx = idx;
        } else if (seg < 24) {
            int co = (seg - 16) * 16 + lco;
            v = w_org[((size_t)co * Cc + ci) * 9 + tap];
            dst = wpkO; didx = idx - 16 * 18432;
        } else {
            int co = (seg - 24) * 16 + lco;
            if (co < 18)      v = w_off[((size_t)co * Cc + ci) * 9 + tap];
            else if (co < 27) v = w_mask[((size_t)(co - 18) * Cc + ci) * 9 + tap];
            dst = wpkOM; didx = idx - 24 * 18432;
        }
        dst[didx] = f2bf(v);
    } else if (idx < TOT + 32) {
        int j = idx - TOT;
        bom[j] = (j < 18) ? b_off[j] : (j < 27 ? b_mask[j - 18] : 0.f);
    }
}

// ---- x (NCHW f32) -> dst (NHWC bf16, guarded base) ----
__global__ __launch_bounds__(256) void tobf_k(const float* __restrict__ x,
                                              unsigned short* __restrict__ dst) {
    const int h = blockIdx.x, b = blockIdx.y;
    const int t = threadIdx.x;
    __shared__ unsigned short lt[16][128];
    const int ciq = t >> 4, wg = t & 15;
    const int w = t >> 1, half = t & 1;
    for (int s = 0; s < 8; s++) {
        const float* p = x + ((size_t)(b * 128 + s * 16 + ciq) * HW + h * 128 + wg * 8);
        float4 a = *(const float4*)p;
        float4 c = *(const float4*)(p + 4);
        *(uint4*)&lt[ciq][wg * 8] =
            make_uint4(cvtpk(a.x, a.y), cvtpk(a.z, a.w), cvtpk(c.x, c.y), cvtpk(c.z, c.w));
        __syncthreads();
        unsigned r[4];
#pragma unroll
        for (int k = 0; k < 4; k++) {
            unsigned lo = lt[half * 8 + 2 * k][w];
            unsigned hi = lt[half * 8 + 2 * k + 1][w];
            r[k] = lo | (hi << 16);
        }
        *(uint4*)(dst + ((size_t)b * HW + h * 128 + w) * 128 + s * 16 + half * 8) =
            make_uint4(r[0], r[1], r[2], r[3]);
        __syncthreads();
    }
}

// ---- MFMA implicit-GEMM conv3x3 (pad=1), global_load_lds + afr ping-pong,
//      (rowr,dx)-loop B-fragment reuse ----
template <int COTPB, int WCO, bool SWZ>
__global__ __launch_bounds__(256, 2) void conv3_k(
    const unsigned short* __restrict__ src, const unsigned short* __restrict__ wpk,
    const float* __restrict__ biasA, const float* __restrict__ biasB,
    int bsplit, int sigsplit,
    float* __restrict__ out, int ldc, int ch0) {
    constexpr int ROWS = 2;
    constexpr int WPX = 4 / WCO;
    constexpr int PXW = 128 / WPX;
    constexpr int PS = PXW / 16;
    constexpr int HB = 128 / ROWS;

    const int t = threadIdx.x;
    const int lane = t & 63, llo = t & 15, lhi = (t >> 4) & 3;
    const int widu = __builtin_amdgcn_readfirstlane(t >> 6);
    const int wr = widu / WPX, wc = widu % WPX;

    int cbi, h0, b;
    if (SWZ) {
        int n = blockIdx.x;
        int xcd = n & 7, j = n >> 3;
        int g = (j >> 2) * 8 + xcd;
        cbi = j & 3;
        h0 = (g % HB) * ROWS;
        b = g / HB;
    } else {
        cbi = 0;
        h0 = ((int)blockIdx.x % HB) * ROWS;
        b = (int)blockIdx.x / HB;
    }
    const int cotbase = cbi * COTPB + wr * 2;

    __shared__ unsigned short xs[2][4][4][128][8];  // 64 KB

    floatx4 acc[2][ROWS][PS];
#pragma unroll
    for (int c = 0; c < 2; c++)
#pragma unroll
        for (int row = 0; row < ROWS; row++)
#pragma unroll
            for (int ps = 0; ps < PS; ps++) acc[c][row][ps] = (floatx4){0.f, 0.f, 0.f, 0.f};

    const unsigned short* srcb = src + ((size_t)b * HW + (size_t)(h0 - 1) * 128) * 128;

    auto stage = [&](int chunk, int buf) {
        const unsigned short* sb = srcb + chunk * 32 + widu * 8;
        unsigned short* db = &xs[buf][widu][0][0][0];
#pragma unroll
        for (int i = 0; i < 8; i++) {
            const unsigned short* g = sb + (size_t)(i * 64 + lane) * 128;
            gload16(g, db + i * 512);
        }
    };

    short8v afrA[9][2], afrB[9][2];
    auto loadafr = [&](int chunk, short8v (*dst)[2]) {
#pragma unroll
        for (int tap = 0; tap < 9; tap++)
#pragma unroll
            for (int c = 0; c < 2; c++)
                dst[tap][c] = *(const short8v*)(wpk +
                    ((((size_t)(cotbase + c) * 4 + chunk) * 9 + tap) * 64 + lane) * 8);
    };

    stage(0, 0);
    loadafr(0, afrA);
    __syncthreads();

    const int wcb = wc * PXW;
#pragma unroll
    for (int chunk = 0; chunk < 4; ++chunk) {
        const int buf = chunk & 1;
        if (chunk < 3) {
            stage(chunk + 1, buf ^ 1);
            loadafr(chunk + 1, (chunk & 1) ? afrA : afrB);
        }
        short8v (*cur)[2] = (chunk & 1) ? afrB : afrA;
#pragma unroll
        for (int rowr = 0; rowr < ROWS + 2; ++rowr) {
            const int hh = h0 - 1 + rowr;
            if ((unsigned)hh < 128u) {
#pragma unroll
                for (int dx = 0; dx < 3; ++dx) {
#pragma unroll
                    for (int ps = 0; ps < PS; ps++) {
                        int colr = wcb + ps * 16 + llo + dx - 1;
                        int colc = min(max(colr, 0), 127);
                        short8v bfv = *(const short8v*)&xs[buf][lhi][rowr][colc][0];
                        if (colr != colc) bfv = (short8v)(short)0;
#pragma unroll
                        for (int row = 0; row < ROWS; ++row) {
                            const int r = rowr - row;
                            if (r >= 0 && r < 3) {
                                const int tap = r * 3 + dx;
#pragma unroll
                                for (int c = 0; c < 2; c++)
                                    acc[c][row][ps] = MFMA16(cur[tap][c], bfv, acc[c][row][ps]);
                            }
                        }
                    }
                }
            }
        }
        __syncthreads();
    }

    const int cbase = cbi * (COTPB * 16);
    const float* bp = (cbase < bsplit) ? biasA : biasB;
    const int bshift = (cbase < bsplit) ? 0 : bsplit;
    const bool dosig = cbase < sigsplit;
#pragma unroll
    for (int c = 0; c < 2; c++)
#pragma unroll
        for (int row = 0; row < ROWS; row++)
#pragma unroll
            for (int ps = 0; ps < PS; ps++)
#pragma unroll
                for (int reg = 0; reg < 4; reg++) {
                    int co = cbase + (wr * 2 + c) * 16 + lhi * 4 + reg;
                    int px = wc * PXW + ps * 16 + llo;
                    float v = acc[c][row][ps][reg] + bp[co - bshift];
                    if (dosig) v = sigmoidf_(v);
                    out[((size_t)b * ldc + ch0 + co) * HW + (h0 + row) * Wd + px] = v;
                }
}

// ---- instance-norm stats ----
__global__ __launch_bounds__(256) void inorm_stats_k(const float* __restrict__ src,
                                                     float* __restrict__ mu, float* __restrict__ rsig,
                                                     int chTot, int ch0) {
    const int bc = blockIdx.x;
    const int b = bc >> 7, c = bc & 127;
    const float4* p = (const float4*)(src + ((size_t)b * chTot + ch0 + c) * HW);
    float s = 0.f, s2 = 0.f;
    for (int i = threadIdx.x; i < HW / 4; i += BDIM) {
        float4 v = p[i];
        s += v.x + v.y + v.z + v.w;
        s2 += v.x * v.x + v.y * v.y + v.z * v.z + v.w * v.w;
    }
    __shared__ float ss[BDIM], sq[BDIM];
    int t = threadIdx.x;
    ss[t] = s; sq[t] = s2;
    __syncthreads();
    for (int off = BDIM / 2; off > 0; off >>= 1) {
        if (t < off) { ss[t] += ss[t + off]; sq[t] += sq[t + off]; }
        __syncthreads();
    }
    if (t == 0) {
        float m = ss[0] / HW;
        float var = sq[0] / HW - m * m;
        mu[bc] = m;
        rsig[bc] = rsqrtf(var + EPSv);
    }
}

// ---- xa = lrelu(norm(featRaw)) * attn -> xabf (NHWC bf16, guarded base) ----
__global__ __launch_bounds__(256) void xattned2_k(const float* __restrict__ rawAF,
                                                  const float* __restrict__ mu,
                                                  const float* __restrict__ rsig,
                                                  unsigned short* __restrict__ xabfG) {
    const int seg = blockIdx.x, h = blockIdx.y, b = blockIdx.z;
    const int t = threadIdx.x;
    __shared__ unsigned short la[64][128];
    const int px4 = t & 15, cl = t >> 4;
#pragma unroll
    for (int p = 0; p < 8; p++) {
        int c = p * 16 + cl;
        int plane = b * 128 + c;
        size_t pixo = (size_t)h * Wd + seg * 64 + px4 * 4;
        float4 a = *(const float4*)(rawAF + ((size_t)b * 256 + c) * HW + pixo);
        float4 f = *(const float4*)(rawAF + ((size_t)b * 256 + 128 + c) * HW + pixo);
        float m = mu[plane], rs = rsig[plane];
        float vs[4];
        float v;
        v = (f.x - m) * rs; v = v > 0.f ? v : 0.2f * v; vs[0] = v * a.x;
        v = (f.y - m) * rs; v = v > 0.f ? v : 0.2f * v; vs[1] = v * a.y;
        v = (f.z - m) * rs; v = v > 0.f ? v : 0.2f * v; vs[2] = v * a.z;
        v = (f.w - m) * rs; v = v > 0.f ? v : 0.2f * v; vs[3] = v * a.w;
#pragma unroll
        for (int j = 0; j < 4; j++) la[px4 * 4 + j][c] = f2bf(vs[j]);
    }
    __syncthreads();
    const int px = t >> 2, part = t & 3;
    const uint4* lp = (const uint4*)&la[px][part * 32];
    unsigned short* dp = xabfG + ((size_t)b * HW + h * 128 + seg * 64 + px) * 128 + part * 32;
    uint4 v0 = lp[0], v1 = lp[1], v2 = lp[2], v3 = lp[3];
    *(uint4*)dp = v0;
    *(uint4*)(dp + 8) = v1;
    *(uint4*)(dp + 16) = v2;
    *(uint4*)(dp + 24) = v3;
}

// ---- deformable conv, 32-px blocks (r13 config: grp-planar xt, b32 pointer-walk gather).
//      (256,4) is the stable point: (256,6) and 64-px tiles both force scratch spill
//      (r9/r17: VGPR->40, WRITE 240MB); wider reg batches also spill (r14/r15). ----
__global__ __launch_bounds__(256, 4) void deform_mfma_k(
    const unsigned short* __restrict__ xabfG, const float* __restrict__ om,
    const unsigned short* __restrict__ wpkO, const float* __restrict__ b_org,
    float* __restrict__ out, int ldc, int ch0) {
    const int seg = blockIdx.x, h = blockIdx.y, b = blockIdx.z;
    const int t = threadIdx.x;
    const int lane = t & 63, llo = t & 15, lhi = (t >> 4) & 3;
    const int wid = t >> 6;
    const int cb = seg * 32;

    __shared__ unsigned short sv[4][9][32][8];
    __shared__ unsigned xt[8 * 6 * 40];

    int prA[2][4];
    float prW[2][4];
    int prT0[2], prOff[2];
    bool prV[2], prOK[2];

    const float* omb = om + (size_t)b * 32 * HW;
#pragma unroll
    for (int u = 0; u < 2; u++) {
        bool valid;
        int pc;
        if (u == 0) { valid = true; pc = t; }
        else { valid = t < 32; pc = 256 + (t & 31); }
        int tap = pc >> 5, pxl = pc & 31;
        int ww = cb + pxl;
        int pix = h * Wd + ww;
        float dy = omb[(size_t)(2 * tap) * HW + pix];
        float dxv = omb[(size_t)(2 * tap + 1) * HW + pix];
        float msk = sigmoidf_(omb[(size_t)(18 + tap) * HW + pix]);
        float yy = dy + (float)(h + tap / 3 - 1);
        float xx = dxv + (float)(ww + tap % 3 - 1);
        float y0f = floorf(yy), x0f = floorf(xx);
        float wy = yy - y0f, wx = xx - x0f;
        int y0 = (int)y0f, x0 = (int)x0f;
#pragma unroll
        for (int c2 = 0; c2 < 4; c2++) {
            int ddy = c2 >> 1, ddx = c2 & 1;
            int yi = y0 + ddy, xi = x0 + ddx;
            bool vc = (yi >= 0) && (yi < Hh) && (xi >= 0) && (xi < Wd);
            int yc = min(max(yi, 0), Hh - 1), xc = min(max(xi, 0), Wd - 1);
            float wt = (ddy ? wy : 1.f - wy) * (ddx ? wx : 1.f - wx);
            prA[u][c2] = yc * Wd + xc;
            prW[u][c2] = vc ? wt * msk : 0.f;
        }
        int ty0 = y0 - (h - 2);
        int tx0 = x0 - (cb - 2);
        prOK[u] = ((unsigned)ty0 <= 4u) && ((unsigned)tx0 <= 38u);
        prT0[u] = ty0 * 40 + tx0;
        prOff[u] = tap * 32 + pxl;
        prV[u] = valid;
    }

    floatx4 acc[2][2];
#pragma unroll
    for (int c = 0; c < 2; c++)
#pragma unroll
        for (int ps = 0; ps < 2; ps++) acc[c][ps] = (floatx4){0.f, 0.f, 0.f, 0.f};

    const unsigned short* xab = xabfG + (size_t)b * HW * 128;
    unsigned short* svf = &sv[0][0][0][0];

    uint4 U[2];

    auto issue_stage = [&](int nc) {
        const int cbase = nc * 16;
#pragma unroll
        for (int it = 0; it < 2; it++) {
            int task = t + it * 256;
            if (task < 480) {
                int col = task % 40;
                int rg = task / 40;
                int row = rg % 6, grp = rg / 6;
                int r = h - 2 + row, cX = cb - 2 + col;
                int rc = min(max(r, 0), Hh - 1), cc = min(max(cX, 0), Wd - 1);
                U[it] = *(const uint4*)(xab + ((size_t)rc * 128 + cc) * 128 + cbase + grp * 8);
            }
        }
    };

    issue_stage(0);

    for (int chunk = 0; chunk < 4; ++chunk) {
#pragma unroll
        for (int half = 0; half < 2; ++half) {
            barrier_lgkm();
#pragma unroll
            for (int it = 0; it < 2; it++) {
                int task = t + it * 256;
                if (task < 480) {
                    int col = task % 40;
                    int rg = task / 40;
                    int row = rg % 6, grp = rg / 6;
                    int cell = row * 40 + col;
                    xt[(grp * 4 + 0) * 240 + cell] = U[it].x;
                    xt[(grp * 4 + 1) * 240 + cell] = U[it].y;
                    xt[(grp * 4 + 2) * 240 + cell] = U[it].z;
                    xt[(grp * 4 + 3) * 240 + cell] = U[it].w;
                }
            }
            int nc = chunk * 2 + half + 1;
            if (nc < 8) issue_stage(nc);
            barrier_lgkm();
#pragma unroll
            for (int u = 0; u < 2; u++) {
                if (!prV[u]) continue;
                const float w0 = prW[u][0], w1 = prW[u][1], w2 = prW[u][2], w3 = prW[u][3];
                if (prOK[u]) {
                    const unsigned* xp = xt + prT0[u];
                    unsigned q[8];
#pragma unroll
                    for (int c2 = 0; c2 < 8; c2++) {
                        unsigned c00 = xp[0], c01 = xp[1];
                        unsigned c10 = xp[40], c11 = xp[41];
                        float2v s = unpk2(c00) * w0 + unpk2(c01) * w1
                                  + unpk2(c10) * w2 + unpk2(c11) * w3;
                        q[c2] = cvtpk(s[0], s[1]);
                        xp += 240;
                    }
                    *(uint4*)(svf + ((size_t)((half * 2 + 0) * 288 + prOff[u]) << 3)) =
                        make_uint4(q[0], q[1], q[2], q[3]);
                    *(uint4*)(svf + ((size_t)((half * 2 + 1) * 288 + prOff[u]) << 3)) =
                        make_uint4(q[4], q[5], q[6], q[7]);
                } else {
                    const int a0 = prA[u][0], a1 = prA[u][1], a2 = prA[u][2], a3 = prA[u][3];
                    const int cch = chunk * 32 + half * 16;
#pragma unroll
                    for (int cg2 = 0; cg2 < 2; cg2++) {
                        unsigned q[4];
#pragma unroll
                        for (int pair = 0; pair < 4; pair++) {
                            int co8 = cch + cg2 * 8 + 2 * pair;
                            unsigned c0 = *(const unsigned*)(xab + (size_t)a0 * 128 + co8);
                            unsigned c1 = *(const unsigned*)(xab + (size_t)a1 * 128 + co8);
                            unsigned c2v = *(const unsigned*)(xab + (size_t)a2 * 128 + co8);
                            unsigned c3 = *(const unsigned*)(xab + (size_t)a3 * 128 + co8);
                            float2v s = unpk2(c0) * w0 + unpk2(c1) * w1
                                      + unpk2(c2v) * w2 + unpk2(c3) * w3;
                            q[pair] = cvtpk(s[0], s[1]);
                        }
                        *(uint4*)(svf + ((size_t)((half * 2 + cg2) * 288 + prOff[u]) << 3)) =
                            make_uint4(q[0], q[1], q[2], q[3]);
                    }
                }
            }
        }
        barrier_lgkm();
#pragma unroll
        for (int tap = 0; tap < 9; ++tap) {
            short8v af[2];
#pragma unroll
            for (int c = 0; c < 2; c++) {
                int cot = wid * 2 + c;
                af[c] = *(const short8v*)(wpkO + ((((size_t)cot * 4 + chunk) * 9 + tap) * 64 + lane) * 8);
            }
            short8v bf[2];
#pragma unroll
            for (int ps = 0; ps < 2; ps++)
                bf[ps] = *(const short8v*)&sv[lhi][tap][ps * 16 + llo][0];
#pragma unroll
            for (int c = 0; c < 2; c++)
#pragma unroll
                for (int ps = 0; ps < 2; ps++)
                    acc[c][ps] = MFMA16(af[c], bf[ps], acc[c][ps]);
        }
    }

#pragma unroll
    for (int c = 0; c < 2; c++)
#pragma unroll
        for (int ps = 0; ps < 2; ps++)
#pragma unroll
            for (int reg = 0; reg < 4; reg++) {
                int co = (wid * 2 + c) * 16 + lhi * 4 + reg;
                int px = cb + ps * 16 + llo;
                out[((size_t)b * ldc + ch0 + co) * HW + h * Wd + px] = acc[c][ps][reg] + b_org[co];
            }
}

// ---- out = xa + lrelu(norm(dconv)) * (1 - attn) ; xa from xabf via LDS ----
__global__ __launch_bounds__(256) void final2_k(const float* __restrict__ rawAF,
                                                const unsigned short* __restrict__ xabfG,
                                                const float* __restrict__ mu,
                                                const float* __restrict__ rsig,
                                                float* __restrict__ outp) {
    const int seg = blockIdx.x, h = blockIdx.y, b = blockIdx.z;
    const int t = threadIdx.x;
    __shared__ unsigned short la[64][128];
    {
        const int px = t >> 2, part = t & 3;
        const unsigned short* sp = xabfG + ((size_t)b * HW + h * 128 + seg * 64 + px) * 128 + part * 32;
        uint4* lp = (uint4*)&la[px][part * 32];
        lp[0] = *(const uint4*)sp;
        lp[1] = *(const uint4*)(sp + 8);
        lp[2] = *(const uint4*)(sp + 16);
        lp[3] = *(const uint4*)(sp + 24);
    }
    __syncthreads();
    const int px4 = t & 15, cl = t >> 4;
#pragma unroll
    for (int p = 0; p < 8; p++) {
        int c = p * 16 + cl;
        int plane = b * 128 + c;
        size_t pixo = (size_t)h * Wd + seg * 64 + px4 * 4;
        float4 a = *(const float4*)(rawAF + ((size_t)b * 256 + c) * HW + pixo);
        float4 d = *(const float4*)(rawAF + ((size_t)b * 256 + 128 + c) * HW + pixo);
        float m = mu[plane], rs = rsig[plane];
        float4 o;
        float v;
        v = (d.x - m) * rs; v = v > 0.f ? v : 0.2f * v; o.x = bfu(la[px4 * 4 + 0][c]) + v * (1.f - a.x);
        v = (d.y - m) * rs; v = v > 0.f ? v : 0.2f * v; o.y = bfu(la[px4 * 4 + 1][c]) + v * (1.f - a.y);
        v = (d.z - m) * rs; v = v > 0.f ? v : 0.2f * v; o.z = bfu(la[px4 * 4 + 2][c]) + v * (1.f - a.z);
        v = (d.w - m) * rs; v = v > 0.f ? v : 0.2f * v; o.w = bfu(la[px4 * 4 + 3][c]) + v * (1.f - a.w);
        *(float4*)(outp + (size_t)plane * HW + pixo) = o;
    }
}

extern "C" void kernel_launch(void* const* d_in, const int* in_sizes, int n_in,
                              void* d_out, int out_size, void* d_ws, size_t ws_size,
                              hipStream_t stream) {
    const float* x      = (const float*)d_in[0];
    const float* w_attn = (const float*)d_in[1];
    const float* b_attn = (const float*)d_in[2];
    const float* w_feat = (const float*)d_in[3];
    const float* b_feat = (const float*)d_in[4];
    const float* w_org  = (const float*)d_in[5];
    const float* b_org  = (const float*)d_in[6];
    const float* w_off  = (const float*)d_in[7];
    const float* b_off  = (const float*)d_in[8];
    const float* w_mask = (const float*)d_in[9];
    const float* b_mask = (const float*)d_in[10];
    float* out = (float*)d_out;
    (void)in_sizes; (void)n_in; (void)out_size; (void)ws_size;

    float* ws = (float*)d_ws;
    float* rawAF = ws;
    unsigned short* regionA = (unsigned short*)(ws + (size_t)BB * 256 * HW);
    unsigned short* xbfG  = regionA + 16384;             // aliased: x-bf16 then xa-bf16
    const size_t bfElems = (size_t)BB * HW * 128;
    float* offm = (float*)(regionA + 2 * 16384 + bfElems);
    float* tail = offm + (size_t)BB * 32 * HW;
    unsigned short* wpkAF = (unsigned short*)tail;
    unsigned short* wpkO  = wpkAF + (size_t)16 * 18432;
    unsigned short* wpkOM = wpkO + (size_t)8 * 18432;
    float* bOM = (float*)(wpkOM + (size_t)2 * 18432);
    float* mu1 = bOM + 32;
    float* rs1 = mu1 + 512;
    float* mu2 = rs1 + 512;
    float* rs2 = mu2 + 512;

    repack_all_k<<<(26 * 18432 + 32 + BDIM - 1) / BDIM, BDIM, 0, stream>>>(
        w_attn, w_feat, w_org, w_off, w_mask, b_off, b_mask, wpkAF, wpkO, wpkOM, bOM);

    tobf_k<<<dim3(Hh, BB), BDIM, 0, stream>>>(x, xbfG);

    conv3_k<4, 2, true><<<1024, BDIM, 0, stream>>>(
        xbfG, wpkAF, b_attn, b_feat, 128, 128, rawAF, 256, 0);

    inorm_stats_k<<<BB * Cc, BDIM, 0, stream>>>(rawAF, mu1, rs1, 256, 128);

    xattned2_k<<<dim3(2, Hh, BB), BDIM, 0, stream>>>(rawAF, mu1, rs1, xbfG);

    conv3_k<2, 1, false><<<256, BDIM, 0, stream>>>(
        xbfG, wpkOM, bOM, bOM, 32, 0, offm, 32, 0);

    deform_mfma_k<<<dim3(4, Hh, BB), BDIM, 0, stream>>>(
        xbfG, offm, wpkO, b_org, rawAF, 256, 128);

    inorm_stats_k<<<BB * Cc, BDIM, 0, stream>>>(rawAF, mu2, rs2, 256, 128);

    final2_k<<<dim3(2, Hh, BB), BDIM, 0, stream>>>(rawAF, xbfG, mu2, rs2, out);
}

// Round 19
// 170.761 us; speedup vs baseline: 1.5532x; 1.0794x over previous
//
#include <hip/hip_runtime.h>
#include <math.h>

#define BDIM 256
constexpr int BB = 4, Cc = 128, Hh = 128, Wd = 128, HW = Hh * Wd;
constexpr float EPSv = 1e-5f;

typedef __attribute__((ext_vector_type(8))) short short8v;
typedef __attribute__((ext_vector_type(4))) float floatx4;
typedef __attribute__((ext_vector_type(2))) float float2v;

#define MFMA16(a, b, c) __builtin_amdgcn_mfma_f32_16x16x32_bf16((a), (b), (c), 0, 0, 0)

__device__ __forceinline__ float sigmoidf_(float v) { return 1.f / (1.f + __expf(-v)); }

__device__ __forceinline__ unsigned short f2bf(float f) {
    union { float f; unsigned u; } v; v.f = f;
    unsigned r = v.u + 0x7FFFu + ((v.u >> 16) & 1u);
    return (unsigned short)(r >> 16);
}
__device__ __forceinline__ unsigned cvtpk(float a, float b) {
    unsigned r;
    asm("v_cvt_pk_bf16_f32 %0, %1, %2" : "=v"(r) : "v"(a), "v"(b));
    return r;
}
__device__ __forceinline__ float bfu(unsigned short u) { union { unsigned u; float f; } v; v.u = ((unsigned)u) << 16; return v.f; }
__device__ __forceinline__ float2v unpk2(unsigned u) {
    union { unsigned x[2]; float2v f; } v;
    v.x[0] = u << 16;
    v.x[1] = u & 0xFFFF0000u;
    return v.f;
}

// LDS-only barrier: does NOT drain vmcnt (in-flight prefetch survives).
__device__ __forceinline__ void barrier_lgkm() {
    asm volatile("s_waitcnt lgkmcnt(0)" ::: "memory");
    __builtin_amdgcn_s_barrier();
}

// async global->LDS, 16B per lane; lds dest = uniform base + lane*16
__device__ __forceinline__ void gload16(const void* g, void* l) {
    __builtin_amdgcn_global_load_lds(
        (const __attribute__((address_space(1))) unsigned int*)g,
        (__attribute__((address_space(3))) unsigned int*)l, 16, 0, 0);
}

// ---- all weight repacks fused: wpkAF(attn|feat), wpkO, wpkOM, bom ----
__global__ void repack_all_k(const float* __restrict__ w_attn, const float* __restrict__ w_feat,
                             const float* __restrict__ w_org, const float* __restrict__ w_off,
                             const float* __restrict__ w_mask, const float* __restrict__ b_off,
                             const float* __restrict__ b_mask,
                             unsigned short* __restrict__ wpkAF, unsigned short* __restrict__ wpkO,
                             unsigned short* __restrict__ wpkOM, float* __restrict__ bom) {
    int idx = blockIdx.x * BDIM + threadIdx.x;
    const int TOT = 26 * 18432;
    if (idx < TOT) {
        int seg = idx / 18432, rem = idx % 18432;
        int i = rem & 7, lane = (rem >> 3) & 63, tap = (rem >> 9) % 9, chunk = rem / (9 * 512);
        int lco = lane & 15;
        int ci = chunk * 32 + (lane >> 4) * 8 + i;
        float v = 0.f;
        unsigned short* dst;
        int didx;
        if (seg < 16) {
            int cot = seg & 7;
            const float* w = (seg < 8) ? w_attn : w_feat;
            int co = cot * 16 + lco;
            v = w[((size_t)co * Cc + ci) * 9 + tap];
            dst = wpkAF; didx = idx;
        } else if (seg < 24) {
            int co = (seg - 16) * 16 + lco;
            v = w_org[((size_t)co * Cc + ci) * 9 + tap];
            dst = wpkO; didx = idx - 16 * 18432;
        } else {
            int co = (seg - 24) * 16 + lco;
            if (co < 18)      v = w_off[((size_t)co * Cc + ci) * 9 + tap];
            else if (co < 27) v = w_mask[((size_t)(co - 18) * Cc + ci) * 9 + tap];
            dst = wpkOM; didx = idx - 24 * 18432;
        }
        dst[didx] = f2bf(v);
    } else if (idx < TOT + 32) {
        int j = idx - TOT;
        bom[j] = (j < 18) ? b_off[j] : (j < 27 ? b_mask[j - 18] : 0.f);
    }
}

// ---- x (NCHW f32) -> dst (NHWC bf16, guarded base) ----
__global__ __launch_bounds__(256) void tobf_k(const float* __restrict__ x,
                                              unsigned short* __restrict__ dst) {
    const int h = blockIdx.x, b = blockIdx.y;
    const int t = threadIdx.x;
    __shared__ unsigned short lt[16][128];
    const int ciq = t >> 4, wg = t & 15;
    const int w = t >> 1, half = t & 1;
    for (int s = 0; s < 8; s++) {
        const float* p = x + ((size_t)(b * 128 + s * 16 + ciq) * HW + h * 128 + wg * 8);
        float4 a = *(const float4*)p;
        float4 c = *(const float4*)(p + 4);
        *(uint4*)&lt[ciq][wg * 8] =
            make_uint4(cvtpk(a.x, a.y), cvtpk(a.z, a.w), cvtpk(c.x, c.y), cvtpk(c.z, c.w));
        __syncthreads();
        unsigned r[4];
#pragma unroll
        for (int k = 0; k < 4; k++) {
            unsigned lo = lt[half * 8 + 2 * k][w];
            unsigned hi = lt[half * 8 + 2 * k + 1][w];
            r[k] = lo | (hi << 16);
        }
        *(uint4*)(dst + ((size_t)b * HW + h * 128 + w) * 128 + s * 16 + half * 8) =
            make_uint4(r[0], r[1], r[2], r[3]);
        __syncthreads();
    }
}

// ---- MFMA implicit-GEMM conv3x3 (pad=1), global_load_lds + afr ping-pong,
//      (rowr,dx)-loop B-fragment reuse. OUTPUT: bf16 ----
template <int COTPB, int WCO, bool SWZ>
__global__ __launch_bounds__(256, 2) void conv3_k(
    const unsigned short* __restrict__ src, const unsigned short* __restrict__ wpk,
    const float* __restrict__ biasA, const float* __restrict__ biasB,
    int bsplit, int sigsplit,
    unsigned short* __restrict__ out, int ldc, int ch0) {
    constexpr int ROWS = 2;
    constexpr int WPX = 4 / WCO;
    constexpr int PXW = 128 / WPX;
    constexpr int PS = PXW / 16;
    constexpr int HB = 128 / ROWS;

    const int t = threadIdx.x;
    const int lane = t & 63, llo = t & 15, lhi = (t >> 4) & 3;
    const int widu = __builtin_amdgcn_readfirstlane(t >> 6);
    const int wr = widu / WPX, wc = widu % WPX;

    int cbi, h0, b;
    if (SWZ) {
        int n = blockIdx.x;
        int xcd = n & 7, j = n >> 3;
        int g = (j >> 2) * 8 + xcd;
        cbi = j & 3;
        h0 = (g % HB) * ROWS;
        b = g / HB;
    } else {
        cbi = 0;
        h0 = ((int)blockIdx.x % HB) * ROWS;
        b = (int)blockIdx.x / HB;
    }
    const int cotbase = cbi * COTPB + wr * 2;

    __shared__ unsigned short xs[2][4][4][128][8];  // 64 KB

    floatx4 acc[2][ROWS][PS];
#pragma unroll
    for (int c = 0; c < 2; c++)
#pragma unroll
        for (int row = 0; row < ROWS; row++)
#pragma unroll
            for (int ps = 0; ps < PS; ps++) acc[c][row][ps] = (floatx4){0.f, 0.f, 0.f, 0.f};

    const unsigned short* srcb = src + ((size_t)b * HW + (size_t)(h0 - 1) * 128) * 128;

    auto stage = [&](int chunk, int buf) {
        const unsigned short* sb = srcb + chunk * 32 + widu * 8;
        unsigned short* db = &xs[buf][widu][0][0][0];
#pragma unroll
        for (int i = 0; i < 8; i++) {
            const unsigned short* g = sb + (size_t)(i * 64 + lane) * 128;
            gload16(g, db + i * 512);
        }
    };

    short8v afrA[9][2], afrB[9][2];
    auto loadafr = [&](int chunk, short8v (*dst)[2]) {
#pragma unroll
        for (int tap = 0; tap < 9; tap++)
#pragma unroll
            for (int c = 0; c < 2; c++)
                dst[tap][c] = *(const short8v*)(wpk +
                    ((((size_t)(cotbase + c) * 4 + chunk) * 9 + tap) * 64 + lane) * 8);
    };

    stage(0, 0);
    loadafr(0, afrA);
    __syncthreads();

    const int wcb = wc * PXW;
#pragma unroll
    for (int chunk = 0; chunk < 4; ++chunk) {
        const int buf = chunk & 1;
        if (chunk < 3) {
            stage(chunk + 1, buf ^ 1);
            loadafr(chunk + 1, (chunk & 1) ? afrA : afrB);
        }
        short8v (*cur)[2] = (chunk & 1) ? afrB : afrA;
#pragma unroll
        for (int rowr = 0; rowr < ROWS + 2; ++rowr) {
            const int hh = h0 - 1 + rowr;
            if ((unsigned)hh < 128u) {
#pragma unroll
                for (int dx = 0; dx < 3; ++dx) {
#pragma unroll
                    for (int ps = 0; ps < PS; ps++) {
                        int colr = wcb + ps * 16 + llo + dx - 1;
                        int colc = min(max(colr, 0), 127);
                        short8v bfv = *(const short8v*)&xs[buf][lhi][rowr][colc][0];
                        if (colr != colc) bfv = (short8v)(short)0;
#pragma unroll
                        for (int row = 0; row < ROWS; ++row) {
                            const int r = rowr - row;
                            if (r >= 0 && r < 3) {
                                const int tap = r * 3 + dx;
#pragma unroll
                                for (int c = 0; c < 2; c++)
                                    acc[c][row][ps] = MFMA16(cur[tap][c], bfv, acc[c][row][ps]);
                            }
                        }
                    }
                }
            }
        }
        __syncthreads();
    }

    const int cbase = cbi * (COTPB * 16);
    const float* bp = (cbase < bsplit) ? biasA : biasB;
    const int bshift = (cbase < bsplit) ? 0 : bsplit;
    const bool dosig = cbase < sigsplit;
#pragma unroll
    for (int c = 0; c < 2; c++)
#pragma unroll
        for (int row = 0; row < ROWS; row++)
#pragma unroll
            for (int ps = 0; ps < PS; ps++)
#pragma unroll
                for (int reg = 0; reg < 4; reg++) {
                    int co = cbase + (wr * 2 + c) * 16 + lhi * 4 + reg;
                    int px = wc * PXW + ps * 16 + llo;
                    float v = acc[c][row][ps][reg] + bp[co - bshift];
                    if (dosig) v = sigmoidf_(v);
                    out[((size_t)b * ldc + ch0 + co) * HW + (h0 + row) * Wd + px] = f2bf(v);
                }
}

// ---- instance-norm stats over bf16 planes ----
__global__ __launch_bounds__(256) void inorm_stats_k(const unsigned short* __restrict__ src,
                                                     float* __restrict__ mu, float* __restrict__ rsig,
                                                     int chTot, int ch0) {
    const int bc = blockIdx.x;
    const int b = bc >> 7, c = bc & 127;
    const unsigned short* p = src + ((size_t)b * chTot + ch0 + c) * HW;
    float s = 0.f, s2 = 0.f;
    for (int i = threadIdx.x; i < HW / 8; i += BDIM) {
        uint4 v = *(const uint4*)(p + (size_t)i * 8);
        float2v a = unpk2(v.x), bb = unpk2(v.y), cc = unpk2(v.z), dd = unpk2(v.w);
        s += a[0] + a[1] + bb[0] + bb[1] + cc[0] + cc[1] + dd[0] + dd[1];
        s2 += a[0] * a[0] + a[1] * a[1] + bb[0] * bb[0] + bb[1] * bb[1]
            + cc[0] * cc[0] + cc[1] * cc[1] + dd[0] * dd[0] + dd[1] * dd[1];
    }
    __shared__ float ss[BDIM], sq[BDIM];
    int t = threadIdx.x;
    ss[t] = s; sq[t] = s2;
    __syncthreads();
    for (int off = BDIM / 2; off > 0; off >>= 1) {
        if (t < off) { ss[t] += ss[t + off]; sq[t] += sq[t + off]; }
        __syncthreads();
    }
    if (t == 0) {
        float m = ss[0] / HW;
        float var = sq[0] / HW - m * m;
        mu[bc] = m;
        rsig[bc] = rsqrtf(var + EPSv);
    }
}

// ---- xa = lrelu(norm(featRaw)) * attn -> xabf (NHWC bf16, guarded base); bf16 inputs ----
__global__ __launch_bounds__(256) void xattned2_k(const unsigned short* __restrict__ rawAF,
                                                  const float* __restrict__ mu,
                                                  const float* __restrict__ rsig,
                                                  unsigned short* __restrict__ xabfG) {
    const int seg = blockIdx.x, h = blockIdx.y, b = blockIdx.z;
    const int t = threadIdx.x;
    __shared__ unsigned short la[64][128];
    const int px4 = t & 15, cl = t >> 4;
#pragma unroll
    for (int p = 0; p < 8; p++) {
        int c = p * 16 + cl;
        int plane = b * 128 + c;
        size_t pixo = (size_t)h * Wd + seg * 64 + px4 * 4;
        uint2 av = *(const uint2*)(rawAF + ((size_t)b * 256 + c) * HW + pixo);
        uint2 fv = *(const uint2*)(rawAF + ((size_t)b * 256 + 128 + c) * HW + pixo);
        float2v a01 = unpk2(av.x), a23 = unpk2(av.y);
        float2v f01 = unpk2(fv.x), f23 = unpk2(fv.y);
        float m = mu[plane], rs = rsig[plane];
        float vs[4];
        float v;
        v = (f01[0] - m) * rs; v = v > 0.f ? v : 0.2f * v; vs[0] = v * a01[0];
        v = (f01[1] - m) * rs; v = v > 0.f ? v : 0.2f * v; vs[1] = v * a01[1];
        v = (f23[0] - m) * rs; v = v > 0.f ? v : 0.2f * v; vs[2] = v * a23[0];
        v = (f23[1] - m) * rs; v = v > 0.f ? v : 0.2f * v; vs[3] = v * a23[1];
#pragma unroll
        for (int j = 0; j < 4; j++) la[px4 * 4 + j][c] = f2bf(vs[j]);
    }
    __syncthreads();
    const int px = t >> 2, part = t & 3;
    const uint4* lp = (const uint4*)&la[px][part * 32];
    unsigned short* dp = xabfG + ((size_t)b * HW + h * 128 + seg * 64 + px) * 128 + part * 32;
    uint4 v0 = lp[0], v1 = lp[1], v2 = lp[2], v3 = lp[3];
    *(uint4*)dp = v0;
    *(uint4*)(dp + 8) = v1;
    *(uint4*)(dp + 16) = v2;
    *(uint4*)(dp + 24) = v3;
}

// ---- deformable conv, 32-px blocks (r13 config); om bf16, dconv out bf16 ----
__global__ __launch_bounds__(256, 4) void deform_mfma_k(
    const unsigned short* __restrict__ xabfG, const unsigned short* __restrict__ om,
    const unsigned short* __restrict__ wpkO, const float* __restrict__ b_org,
    unsigned short* __restrict__ out, int ldc, int ch0) {
    const int seg = blockIdx.x, h = blockIdx.y, b = blockIdx.z;
    const int t = threadIdx.x;
    const int lane = t & 63, llo = t & 15, lhi = (t >> 4) & 3;
    const int wid = t >> 6;
    const int cb = seg * 32;

    __shared__ unsigned short sv[4][9][32][8];
    __shared__ unsigned xt[8 * 6 * 40];

    int prA[2][4];
    float prW[2][4];
    int prT0[2], prOff[2];
    bool prV[2], prOK[2];

    const unsigned short* omb = om + (size_t)b * 32 * HW;
#pragma unroll
    for (int u = 0; u < 2; u++) {
        bool valid;
        int pc;
        if (u == 0) { valid = true; pc = t; }
        else { valid = t < 32; pc = 256 + (t & 31); }
        int tap = pc >> 5, pxl = pc & 31;
        int ww = cb + pxl;
        int pix = h * Wd + ww;
        float dy = bfu(omb[(size_t)(2 * tap) * HW + pix]);
        float dxv = bfu(omb[(size_t)(2 * tap + 1) * HW + pix]);
        float msk = sigmoidf_(bfu(omb[(size_t)(18 + tap) * HW + pix]));
        float yy = dy + (float)(h + tap / 3 - 1);
        float xx = dxv + (float)(ww + tap % 3 - 1);
        float y0f = floorf(yy), x0f = floorf(xx);
        float wy = yy - y0f, wx = xx - x0f;
        int y0 = (int)y0f, x0 = (int)x0f;
#pragma unroll
        for (int c2 = 0; c2 < 4; c2++) {
            int ddy = c2 >> 1, ddx = c2 & 1;
            int yi = y0 + ddy, xi = x0 + ddx;
            bool vc = (yi >= 0) && (yi < Hh) && (xi >= 0) && (xi < Wd);
            int yc = min(max(yi, 0), Hh - 1), xc = min(max(xi, 0), Wd - 1);
            float wt = (ddy ? wy : 1.f - wy) * (ddx ? wx : 1.f - wx);
            prA[u][c2] = yc * Wd + xc;
            prW[u][c2] = vc ? wt * msk : 0.f;
        }
        int ty0 = y0 - (h - 2);
        int tx0 = x0 - (cb - 2);
        prOK[u] = ((unsigned)ty0 <= 4u) && ((unsigned)tx0 <= 38u);
        prT0[u] = ty0 * 40 + tx0;
        prOff[u] = tap * 32 + pxl;
        prV[u] = valid;
    }

    floatx4 acc[2][2];
#pragma unroll
    for (int c = 0; c < 2; c++)
#pragma unroll
        for (int ps = 0; ps < 2; ps++) acc[c][ps] = (floatx4){0.f, 0.f, 0.f, 0.f};

    const unsigned short* xab = xabfG + (size_t)b * HW * 128;
    unsigned short* svf = &sv[0][0][0][0];

    uint4 U[2];

    auto issue_stage = [&](int nc) {
        const int cbase = nc * 16;
#pragma unroll
        for (int it = 0; it < 2; it++) {
            int task = t + it * 256;
            if (task < 480) {
                int col = task % 40;
                int rg = task / 40;
                int row = rg % 6, grp = rg / 6;
                int r = h - 2 + row, cX = cb - 2 + col;
                int rc = min(max(r, 0), Hh - 1), cc = min(max(cX, 0), Wd - 1);
                U[it] = *(const uint4*)(xab + ((size_t)rc * 128 + cc) * 128 + cbase + grp * 8);
            }
        }
    };

    issue_stage(0);

    for (int chunk = 0; chunk < 4; ++chunk) {
#pragma unroll
        for (int half = 0; half < 2; ++half) {
            barrier_lgkm();
#pragma unroll
            for (int it = 0; it < 2; it++) {
                int task = t + it * 256;
                if (task < 480) {
                    int col = task % 40;
                    int rg = task / 40;
                    int row = rg % 6, grp = rg / 6;
                    int cell = row * 40 + col;
                    xt[(grp * 4 + 0) * 240 + cell] = U[it].x;
                    xt[(grp * 4 + 1) * 240 + cell] = U[it].y;
                    xt[(grp * 4 + 2) * 240 + cell] = U[it].z;
                    xt[(grp * 4 + 3) * 240 + cell] = U[it].w;
                }
            }
            int nc = chunk * 2 + half + 1;
            if (nc < 8) issue_stage(nc);
            barrier_lgkm();
#pragma unroll
            for (int u = 0; u < 2; u++) {
                if (!prV[u]) continue;
                const float w0 = prW[u][0], w1 = prW[u][1], w2 = prW[u][2], w3 = prW[u][3];
                if (prOK[u]) {
                    const unsigned* xp = xt + prT0[u];
                    unsigned q[8];
#pragma unroll
                    for (int c2 = 0; c2 < 8; c2++) {
                        unsigned c00 = xp[0], c01 = xp[1];
                        unsigned c10 = xp[40], c11 = xp[41];
                        float2v s = unpk2(c00) * w0 + unpk2(c01) * w1
                                  + unpk2(c10) * w2 + unpk2(c11) * w3;
                        q[c2] = cvtpk(s[0], s[1]);
                        xp += 240;
                    }
                    *(uint4*)(svf + ((size_t)((half * 2 + 0) * 288 + prOff[u]) << 3)) =
                        make_uint4(q[0], q[1], q[2], q[3]);
                    *(uint4*)(svf + ((size_t)((half * 2 + 1) * 288 + prOff[u]) << 3)) =
                        make_uint4(q[4], q[5], q[6], q[7]);
                } else {
                    const int a0 = prA[u][0], a1 = prA[u][1], a2 = prA[u][2], a3 = prA[u][3];
                    const int cch = chunk * 32 + half * 16;
#pragma unroll
                    for (int cg2 = 0; cg2 < 2; cg2++) {
                        unsigned q[4];
#pragma unroll
                        for (int pair = 0; pair < 4; pair++) {
                            int co8 = cch + cg2 * 8 + 2 * pair;
                            unsigned c0 = *(const unsigned*)(xab + (size_t)a0 * 128 + co8);
                            unsigned c1 = *(const unsigned*)(xab + (size_t)a1 * 128 + co8);
                            unsigned c2v = *(const unsigned*)(xab + (size_t)a2 * 128 + co8);
                            unsigned c3 = *(const unsigned*)(xab + (size_t)a3 * 128 + co8);
                            float2v s = unpk2(c0) * w0 + unpk2(c1) * w1
                                      + unpk2(c2v) * w2 + unpk2(c3) * w3;
                            q[pair] = cvtpk(s[0], s[1]);
                        }
                        *(uint4*)(svf + ((size_t)((half * 2 + cg2) * 288 + prOff[u]) << 3)) =
                            make_uint4(q[0], q[1], q[2], q[3]);
                    }
                }
            }
        }
        barrier_lgkm();
#pragma unroll
        for (int tap = 0; tap < 9; ++tap) {
            short8v af[2];
#pragma unroll
            for (int c = 0; c < 2; c++) {
                int cot = wid * 2 + c;
                af[c] = *(const short8v*)(wpkO + ((((size_t)cot * 4 + chunk) * 9 + tap) * 64 + lane) * 8);
            }
            short8v bf[2];
#pragma unroll
            for (int ps = 0; ps < 2; ps++)
                bf[ps] = *(const short8v*)&sv[lhi][tap][ps * 16 + llo][0];
#pragma unroll
            for (int c = 0; c < 2; c++)
#pragma unroll
                for (int ps = 0; ps < 2; ps++)
                    acc[c][ps] = MFMA16(af[c], bf[ps], acc[c][ps]);
        }
    }

#pragma unroll
    for (int c = 0; c < 2; c++)
#pragma unroll
        for (int ps = 0; ps < 2; ps++)
#pragma unroll
            for (int reg = 0; reg < 4; reg++) {
                int co = (wid * 2 + c) * 16 + lhi * 4 + reg;
                int px = cb + ps * 16 + llo;
                out[((size_t)b * ldc + ch0 + co) * HW + h * Wd + px] = f2bf(acc[c][ps][reg] + b_org[co]);
            }
}

// ---- out = xa + lrelu(norm(dconv)) * (1 - attn) ; all intermediates bf16 ----
__global__ __launch_bounds__(256) void final2_k(const unsigned short* __restrict__ rawAF,
                                                const unsigned short* __restrict__ xabfG,
                                                const float* __restrict__ mu,
                                                const float* __restrict__ rsig,
                                                float* __restrict__ outp) {
    const int seg = blockIdx.x, h = blockIdx.y, b = blockIdx.z;
    const int t = threadIdx.x;
    __shared__ unsigned short la[64][128];
    {
        const int px = t >> 2, part = t & 3;
        const unsigned short* sp = xabfG + ((size_t)b * HW + h * 128 + seg * 64 + px) * 128 + part * 32;
        uint4* lp = (uint4*)&la[px][part * 32];
        lp[0] = *(const uint4*)sp;
        lp[1] = *(const uint4*)(sp + 8);
        lp[2] = *(const uint4*)(sp + 16);
        lp[3] = *(const uint4*)(sp + 24);
    }
    __syncthreads();
    const int px4 = t & 15, cl = t >> 4;
#pragma unroll
    for (int p = 0; p < 8; p++) {
        int c = p * 16 + cl;
        int plane = b * 128 + c;
        size_t pixo = (size_t)h * Wd + seg * 64 + px4 * 4;
        uint2 av = *(const uint2*)(rawAF + ((size_t)b * 256 + c) * HW + pixo);
        uint2 dv = *(const uint2*)(rawAF + ((size_t)b * 256 + 128 + c) * HW + pixo);
        float2v a01 = unpk2(av.x), a23 = unpk2(av.y);
        float2v d01 = unpk2(dv.x), d23 = unpk2(dv.y);
        float m = mu[plane], rs = rsig[plane];
        float4 o;
        float v;
        v = (d01[0] - m) * rs; v = v > 0.f ? v : 0.2f * v; o.x = bfu(la[px4 * 4 + 0][c]) + v * (1.f - a01[0]);
        v = (d01[1] - m) * rs; v = v > 0.f ? v : 0.2f * v; o.y = bfu(la[px4 * 4 + 1][c]) + v * (1.f - a01[1]);
        v = (d23[0] - m) * rs; v = v > 0.f ? v : 0.2f * v; o.z = bfu(la[px4 * 4 + 2][c]) + v * (1.f - a23[0]);
        v = (d23[1] - m) * rs; v = v > 0.f ? v : 0.2f * v; o.w = bfu(la[px4 * 4 + 3][c]) + v * (1.f - a23[1]);
        *(float4*)(outp + (size_t)plane * HW + pixo) = o;
    }
}

extern "C" void kernel_launch(void* const* d_in, const int* in_sizes, int n_in,
                              void* d_out, int out_size, void* d_ws, size_t ws_size,
                              hipStream_t stream) {
    const float* x      = (const float*)d_in[0];
    const float* w_attn = (const float*)d_in[1];
    const float* b_attn = (const float*)d_in[2];
    const float* w_feat = (const float*)d_in[3];
    const float* b_feat = (const float*)d_in[4];
    const float* w_org  = (const float*)d_in[5];
    const float* b_org  = (const float*)d_in[6];
    const float* w_off  = (const float*)d_in[7];
    const float* b_off  = (const float*)d_in[8];
    const float* w_mask = (const float*)d_in[9];
    const float* b_mask = (const float*)d_in[10];
    float* out = (float*)d_out;
    (void)in_sizes; (void)n_in; (void)out_size; (void)ws_size;

    float* ws = (float*)d_ws;
    unsigned short* rawAF = (unsigned short*)ws;        // bf16 [b][256][HW]; region half-used
    unsigned short* regionA = (unsigned short*)(ws + (size_t)BB * 256 * HW);
    unsigned short* xbfG  = regionA + 16384;             // aliased: x-bf16 then xa-bf16
    const size_t bfElems = (size_t)BB * HW * 128;
    float* offmF = (float*)(regionA + 2 * 16384 + bfElems);
    unsigned short* offm = (unsigned short*)offmF;      // bf16; region half-used
    float* tail = offmF + (size_t)BB * 32 * HW;
    unsigned short* wpkAF = (unsigned short*)tail;
    unsigned short* wpkO  = wpkAF + (size_t)16 * 18432;
    unsigned short* wpkOM = wpkO + (size_t)8 * 18432;
    float* bOM = (float*)(wpkOM + (size_t)2 * 18432);
    float* mu1 = bOM + 32;
    float* rs1 = mu1 + 512;
    float* mu2 = rs1 + 512;
    float* rs2 = mu2 + 512;

    repack_all_k<<<(26 * 18432 + 32 + BDIM - 1) / BDIM, BDIM, 0, stream>>>(
        w_attn, w_feat, w_org, w_off, w_mask, b_off, b_mask, wpkAF, wpkO, wpkOM, bOM);

    tobf_k<<<dim3(Hh, BB), BDIM, 0, stream>>>(x, xbfG);

    conv3_k<4, 2, true><<<1024, BDIM, 0, stream>>>(
        xbfG, wpkAF, b_attn, b_feat, 128, 128, rawAF, 256, 0);

    inorm_stats_k<<<BB * Cc, BDIM, 0, stream>>>(rawAF, mu1, rs1, 256, 128);

    xattned2_k<<<dim3(2, Hh, BB), BDIM, 0, stream>>>(rawAF, mu1, rs1, xbfG);

    conv3_k<2, 1, false><<<256, BDIM, 0, stream>>>(
        xbfG, wpkOM, bOM, bOM, 32, 0, offm, 32, 0);

    deform_mfma_k<<<dim3(4, Hh, BB), BDIM, 0, stream>>>(
        xbfG, offm, wpkO, b_org, rawAF, 256, 128);

    inorm_stats_k<<<BB * Cc, BDIM, 0, stream>>>(rawAF, mu2, rs2, 256, 128);

    final2_k<<<dim3(2, Hh, BB), BDIM, 0, stream>>>(rawAF, xbfG, mu2, rs2, out);
}

// Round 20
// 169.967 us; speedup vs baseline: 1.5604x; 1.0047x over previous
//
#include <hip/hip_runtime.h>
#include <math.h>

#define BDIM 256
constexpr int BB = 4, Cc = 128, Hh = 128, Wd = 128, HW = Hh * Wd;
constexpr float EPSv = 1e-5f;

typedef __attribute__((ext_vector_type(8))) short short8v;
typedef __attribute__((ext_vector_type(4))) float floatx4;
typedef __attribute__((ext_vector_type(2))) float float2v;

#define MFMA16(a, b, c) __builtin_amdgcn_mfma_f32_16x16x32_bf16((a), (b), (c), 0, 0, 0)

__device__ __forceinline__ float sigmoidf_(float v) { return 1.f / (1.f + __expf(-v)); }

__device__ __forceinline__ unsigned short f2bf(float f) {
    union { float f; unsigned u; } v; v.f = f;
    unsigned r = v.u + 0x7FFFu + ((v.u >> 16) & 1u);
    return (unsigned short)(r >> 16);
}
__device__ __forceinline__ unsigned cvtpk(float a, float b) {
    unsigned r;
    asm("v_cvt_pk_bf16_f32 %0, %1, %2" : "=v"(r) : "v"(a), "v"(b));
    return r;
}
__device__ __forceinline__ float bfu(unsigned short u) { union { unsigned u; float f; } v; v.u = ((unsigned)u) << 16; return v.f; }
__device__ __forceinline__ float2v unpk2(unsigned u) {
    union { unsigned x[2]; float2v f; } v;
    v.x[0] = u << 16;
    v.x[1] = u & 0xFFFF0000u;
    return v.f;
}

// LDS-only barrier: does NOT drain vmcnt (in-flight prefetch survives).
__device__ __forceinline__ void barrier_lgkm() {
    asm volatile("s_waitcnt lgkmcnt(0)" ::: "memory");
    __builtin_amdgcn_s_barrier();
}

// async global->LDS, 16B per lane; lds dest = uniform base + lane*16
__device__ __forceinline__ void gload16(const void* g, void* l) {
    __builtin_amdgcn_global_load_lds(
        (const __attribute__((address_space(1))) unsigned int*)g,
        (__attribute__((address_space(3))) unsigned int*)l, 16, 0, 0);
}

// ---- all weight repacks fused: wpkAF(attn|feat), wpkO, wpkOM, bom ----
__global__ void repack_all_k(const float* __restrict__ w_attn, const float* __restrict__ w_feat,
                             const float* __restrict__ w_org, const float* __restrict__ w_off,
                             const float* __restrict__ w_mask, const float* __restrict__ b_off,
                             const float* __restrict__ b_mask,
                             unsigned short* __restrict__ wpkAF, unsigned short* __restrict__ wpkO,
                             unsigned short* __restrict__ wpkOM, float* __restrict__ bom) {
    int idx = blockIdx.x * BDIM + threadIdx.x;
    const int TOT = 26 * 18432;
    if (idx < TOT) {
        int seg = idx / 18432, rem = idx % 18432;
        int i = rem & 7, lane = (rem >> 3) & 63, tap = (rem >> 9) % 9, chunk = rem / (9 * 512);
        int lco = lane & 15;
        int ci = chunk * 32 + (lane >> 4) * 8 + i;
        float v = 0.f;
        unsigned short* dst;
        int didx;
        if (seg < 16) {
            int cot = seg & 7;
            const float* w = (seg < 8) ? w_attn : w_feat;
            int co = cot * 16 + lco;
            v = w[((size_t)co * Cc + ci) * 9 + tap];
            dst = wpkAF; didx = idx;
        } else if (seg < 24) {
            int co = (seg - 16) * 16 + lco;
            v = w_org[((size_t)co * Cc + ci) * 9 + tap];
            dst = wpkO; didx = idx - 16 * 18432;
        } else {
            int co = (seg - 24) * 16 + lco;
            if (co < 18)      v = w_off[((size_t)co * Cc + ci) * 9 + tap];
            else if (co < 27) v = w_mask[((size_t)(co - 18) * Cc + ci) * 9 + tap];
            dst = wpkOM; didx = idx - 24 * 18432;
        }
        dst[didx] = f2bf(v);
    } else if (idx < TOT + 32) {
        int j = idx - TOT;
        bom[j] = (j < 18) ? b_off[j] : (j < 27 ? b_mask[j - 18] : 0.f);
    }
}

// ---- x (NCHW f32) -> dst (NHWC bf16, guarded base) ----
__global__ __launch_bounds__(256) void tobf_k(const float* __restrict__ x,
                                              unsigned short* __restrict__ dst) {
    const int h = blockIdx.x, b = blockIdx.y;
    const int t = threadIdx.x;
    __shared__ unsigned short lt[16][128];
    const int ciq = t >> 4, wg = t & 15;
    const int w = t >> 1, half = t & 1;
    for (int s = 0; s < 8; s++) {
        const float* p = x + ((size_t)(b * 128 + s * 16 + ciq) * HW + h * 128 + wg * 8);
        float4 a = *(const float4*)p;
        float4 c = *(const float4*)(p + 4);
        *(uint4*)&lt[ciq][wg * 8] =
            make_uint4(cvtpk(a.x, a.y), cvtpk(a.z, a.w), cvtpk(c.x, c.y), cvtpk(c.z, c.w));
        __syncthreads();
        unsigned r[4];
#pragma unroll
        for (int k = 0; k < 4; k++) {
            unsigned lo = lt[half * 8 + 2 * k][w];
            unsigned hi = lt[half * 8 + 2 * k + 1][w];
            r[k] = lo | (hi << 16);
        }
        *(uint4*)(dst + ((size_t)b * HW + h * 128 + w) * 128 + s * 16 + half * 8) =
            make_uint4(r[0], r[1], r[2], r[3]);
        __syncthreads();
    }
}

// ---- MFMA implicit-GEMM conv3x3 (pad=1), global_load_lds + afr ping-pong,
//      (rowr,dx)-loop B-fragment reuse. OUTPUT: bf16 ----
template <int COTPB, int WCO, bool SWZ>
__global__ __launch_bounds__(256, 2) void conv3_k(
    const unsigned short* __restrict__ src, const unsigned short* __restrict__ wpk,
    const float* __restrict__ biasA, const float* __restrict__ biasB,
    int bsplit, int sigsplit,
    unsigned short* __restrict__ out, int ldc, int ch0) {
    constexpr int ROWS = 2;
    constexpr int WPX = 4 / WCO;
    constexpr int PXW = 128 / WPX;
    constexpr int PS = PXW / 16;
    constexpr int HB = 128 / ROWS;

    const int t = threadIdx.x;
    const int lane = t & 63, llo = t & 15, lhi = (t >> 4) & 3;
    const int widu = __builtin_amdgcn_readfirstlane(t >> 6);
    const int wr = widu / WPX, wc = widu % WPX;

    int cbi, h0, b;
    if (SWZ) {
        int n = blockIdx.x;
        int xcd = n & 7, j = n >> 3;
        int g = (j >> 2) * 8 + xcd;
        cbi = j & 3;
        h0 = (g % HB) * ROWS;
        b = g / HB;
    } else {
        cbi = 0;
        h0 = ((int)blockIdx.x % HB) * ROWS;
        b = (int)blockIdx.x / HB;
    }
    const int cotbase = cbi * COTPB + wr * 2;

    __shared__ unsigned short xs[2][4][4][128][8];  // 64 KB

    floatx4 acc[2][ROWS][PS];
#pragma unroll
    for (int c = 0; c < 2; c++)
#pragma unroll
        for (int row = 0; row < ROWS; row++)
#pragma unroll
            for (int ps = 0; ps < PS; ps++) acc[c][row][ps] = (floatx4){0.f, 0.f, 0.f, 0.f};

    const unsigned short* srcb = src + ((size_t)b * HW + (size_t)(h0 - 1) * 128) * 128;

    auto stage = [&](int chunk, int buf) {
        const unsigned short* sb = srcb + chunk * 32 + widu * 8;
        unsigned short* db = &xs[buf][widu][0][0][0];
#pragma unroll
        for (int i = 0; i < 8; i++) {
            const unsigned short* g = sb + (size_t)(i * 64 + lane) * 128;
            gload16(g, db + i * 512);
        }
    };

    short8v afrA[9][2], afrB[9][2];
    auto loadafr = [&](int chunk, short8v (*dst)[2]) {
#pragma unroll
        for (int tap = 0; tap < 9; tap++)
#pragma unroll
            for (int c = 0; c < 2; c++)
                dst[tap][c] = *(const short8v*)(wpk +
                    ((((size_t)(cotbase + c) * 4 + chunk) * 9 + tap) * 64 + lane) * 8);
    };

    stage(0, 0);
    loadafr(0, afrA);
    __syncthreads();

    const int wcb = wc * PXW;
#pragma unroll
    for (int chunk = 0; chunk < 4; ++chunk) {
        const int buf = chunk & 1;
        if (chunk < 3) {
            stage(chunk + 1, buf ^ 1);
            loadafr(chunk + 1, (chunk & 1) ? afrA : afrB);
        }
        short8v (*cur)[2] = (chunk & 1) ? afrB : afrA;
#pragma unroll
        for (int rowr = 0; rowr < ROWS + 2; ++rowr) {
            const int hh = h0 - 1 + rowr;
            if ((unsigned)hh < 128u) {
#pragma unroll
                for (int dx = 0; dx < 3; ++dx) {
#pragma unroll
                    for (int ps = 0; ps < PS; ps++) {
                        int colr = wcb + ps * 16 + llo + dx - 1;
                        int colc = min(max(colr, 0), 127);
                        short8v bfv = *(const short8v*)&xs[buf][lhi][rowr][colc][0];
                        if (colr != colc) bfv = (short8v)(short)0;
#pragma unroll
                        for (int row = 0; row < ROWS; ++row) {
                            const int r = rowr - row;
                            if (r >= 0 && r < 3) {
                                const int tap = r * 3 + dx;
#pragma unroll
                                for (int c = 0; c < 2; c++)
                                    acc[c][row][ps] = MFMA16(cur[tap][c], bfv, acc[c][row][ps]);
                            }
                        }
                    }
                }
            }
        }
        __syncthreads();
    }

    const int cbase = cbi * (COTPB * 16);
    const float* bp = (cbase < bsplit) ? biasA : biasB;
    const int bshift = (cbase < bsplit) ? 0 : bsplit;
    const bool dosig = cbase < sigsplit;
#pragma unroll
    for (int c = 0; c < 2; c++)
#pragma unroll
        for (int row = 0; row < ROWS; row++)
#pragma unroll
            for (int ps = 0; ps < PS; ps++)
#pragma unroll
                for (int reg = 0; reg < 4; reg++) {
                    int co = cbase + (wr * 2 + c) * 16 + lhi * 4 + reg;
                    int px = wc * PXW + ps * 16 + llo;
                    float v = acc[c][row][ps][reg] + bp[co - bshift];
                    if (dosig) v = sigmoidf_(v);
                    out[((size_t)b * ldc + ch0 + co) * HW + (h0 + row) * Wd + px] = f2bf(v);
                }
}

// ---- instance-norm stats over bf16 planes ----
__global__ __launch_bounds__(256) void inorm_stats_k(const unsigned short* __restrict__ src,
                                                     float* __restrict__ mu, float* __restrict__ rsig,
                                                     int chTot, int ch0) {
    const int bc = blockIdx.x;
    const int b = bc >> 7, c = bc & 127;
    const unsigned short* p = src + ((size_t)b * chTot + ch0 + c) * HW;
    float s = 0.f, s2 = 0.f;
    for (int i = threadIdx.x; i < HW / 8; i += BDIM) {
        uint4 v = *(const uint4*)(p + (size_t)i * 8);
        float2v a = unpk2(v.x), bb = unpk2(v.y), cc = unpk2(v.z), dd = unpk2(v.w);
        s += a[0] + a[1] + bb[0] + bb[1] + cc[0] + cc[1] + dd[0] + dd[1];
        s2 += a[0] * a[0] + a[1] * a[1] + bb[0] * bb[0] + bb[1] * bb[1]
            + cc[0] * cc[0] + cc[1] * cc[1] + dd[0] * dd[0] + dd[1] * dd[1];
    }
    __shared__ float ss[BDIM], sq[BDIM];
    int t = threadIdx.x;
    ss[t] = s; sq[t] = s2;
    __syncthreads();
    for (int off = BDIM / 2; off > 0; off >>= 1) {
        if (t < off) { ss[t] += ss[t + off]; sq[t] += sq[t + off]; }
        __syncthreads();
    }
    if (t == 0) {
        float m = ss[0] / HW;
        float var = sq[0] / HW - m * m;
        mu[bc] = m;
        rsig[bc] = rsqrtf(var + EPSv);
    }
}

// ---- xa = lrelu(norm(featRaw)) * attn -> xabf (NHWC bf16, guarded base); bf16 inputs ----
__global__ __launch_bounds__(256) void xattned2_k(const unsigned short* __restrict__ rawAF,
                                                  const float* __restrict__ mu,
                                                  const float* __restrict__ rsig,
                                                  unsigned short* __restrict__ xabfG) {
    const int seg = blockIdx.x, h = blockIdx.y, b = blockIdx.z;
    const int t = threadIdx.x;
    __shared__ unsigned short la[64][128];
    const int px4 = t & 15, cl = t >> 4;
#pragma unroll
    for (int p = 0; p < 8; p++) {
        int c = p * 16 + cl;
        int plane = b * 128 + c;
        size_t pixo = (size_t)h * Wd + seg * 64 + px4 * 4;
        uint2 av = *(const uint2*)(rawAF + ((size_t)b * 256 + c) * HW + pixo);
        uint2 fv = *(const uint2*)(rawAF + ((size_t)b * 256 + 128 + c) * HW + pixo);
        float2v a01 = unpk2(av.x), a23 = unpk2(av.y);
        float2v f01 = unpk2(fv.x), f23 = unpk2(fv.y);
        float m = mu[plane], rs = rsig[plane];
        float vs[4];
        float v;
        v = (f01[0] - m) * rs; v = v > 0.f ? v : 0.2f * v; vs[0] = v * a01[0];
        v = (f01[1] - m) * rs; v = v > 0.f ? v : 0.2f * v; vs[1] = v * a01[1];
        v = (f23[0] - m) * rs; v = v > 0.f ? v : 0.2f * v; vs[2] = v * a23[0];
        v = (f23[1] - m) * rs; v = v > 0.f ? v : 0.2f * v; vs[3] = v * a23[1];
#pragma unroll
        for (int j = 0; j < 4; j++) la[px4 * 4 + j][c] = f2bf(vs[j]);
    }
    __syncthreads();
    const int px = t >> 2, part = t & 3;
    const uint4* lp = (const uint4*)&la[px][part * 32];
    unsigned short* dp = xabfG + ((size_t)b * HW + h * 128 + seg * 64 + px) * 128 + part * 32;
    uint4 v0 = lp[0], v1 = lp[1], v2 = lp[2], v3 = lp[3];
    *(uint4*)dp = v0;
    *(uint4*)(dp + 8) = v1;
    *(uint4*)(dp + 16) = v2;
    *(uint4*)(dp + 24) = v3;
}

// ---- deformable conv, 32-px blocks; xt DOUBLE-BUFFERED (12 barriers/block vs 20).
//      Hazards: write(i)->xt[i&1] last read by gather(i-2), ordered by barrier(i-1);
//      one barrier per half publishes writes before gather; chunk-first barrier orders
//      prev MFMA before sv overwrite. ----
__global__ __launch_bounds__(256, 4) void deform_mfma_k(
    const unsigned short* __restrict__ xabfG, const unsigned short* __restrict__ om,
    const unsigned short* __restrict__ wpkO, const float* __restrict__ b_org,
    unsigned short* __restrict__ out, int ldc, int ch0) {
    const int seg = blockIdx.x, h = blockIdx.y, b = blockIdx.z;
    const int t = threadIdx.x;
    const int lane = t & 63, llo = t & 15, lhi = (t >> 4) & 3;
    const int wid = t >> 6;
    const int cb = seg * 32;

    __shared__ unsigned short sv[4][9][32][8];
    __shared__ unsigned xt[2][8 * 6 * 40];

    int prA[2][4];
    float prW[2][4];
    int prT0[2], prOff[2];
    bool prV[2], prOK[2];

    const unsigned short* omb = om + (size_t)b * 32 * HW;
#pragma unroll
    for (int u = 0; u < 2; u++) {
        bool valid;
        int pc;
        if (u == 0) { valid = true; pc = t; }
        else { valid = t < 32; pc = 256 + (t & 31); }
        int tap = pc >> 5, pxl = pc & 31;
        int ww = cb + pxl;
        int pix = h * Wd + ww;
        float dy = bfu(omb[(size_t)(2 * tap) * HW + pix]);
        float dxv = bfu(omb[(size_t)(2 * tap + 1) * HW + pix]);
        float msk = sigmoidf_(bfu(omb[(size_t)(18 + tap) * HW + pix]));
        float yy = dy + (float)(h + tap / 3 - 1);
        float xx = dxv + (float)(ww + tap % 3 - 1);
        float y0f = floorf(yy), x0f = floorf(xx);
        float wy = yy - y0f, wx = xx - x0f;
        int y0 = (int)y0f, x0 = (int)x0f;
#pragma unroll
        for (int c2 = 0; c2 < 4; c2++) {
            int ddy = c2 >> 1, ddx = c2 & 1;
            int yi = y0 + ddy, xi = x0 + ddx;
            bool vc = (yi >= 0) && (yi < Hh) && (xi >= 0) && (xi < Wd);
            int yc = min(max(yi, 0), Hh - 1), xc = min(max(xi, 0), Wd - 1);
            float wt = (ddy ? wy : 1.f - wy) * (ddx ? wx : 1.f - wx);
            prA[u][c2] = yc * Wd + xc;
            prW[u][c2] = vc ? wt * msk : 0.f;
        }
        int ty0 = y0 - (h - 2);
        int tx0 = x0 - (cb - 2);
        prOK[u] = ((unsigned)ty0 <= 4u) && ((unsigned)tx0 <= 38u);
        prT0[u] = ty0 * 40 + tx0;
        prOff[u] = tap * 32 + pxl;
        prV[u] = valid;
    }

    floatx4 acc[2][2];
#pragma unroll
    for (int c = 0; c < 2; c++)
#pragma unroll
        for (int ps = 0; ps < 2; ps++) acc[c][ps] = (floatx4){0.f, 0.f, 0.f, 0.f};

    const unsigned short* xab = xabfG + (size_t)b * HW * 128;
    unsigned short* svf = &sv[0][0][0][0];

    uint4 U[2];

    auto issue_stage = [&](int nc) {
        const int cbase = nc * 16;
#pragma unroll
        for (int it = 0; it < 2; it++) {
            int task = t + it * 256;
            if (task < 480) {
                int col = task % 40;
                int rg = task / 40;
                int row = rg % 6, grp = rg / 6;
                int r = h - 2 + row, cX = cb - 2 + col;
                int rc = min(max(r, 0), Hh - 1), cc = min(max(cX, 0), Wd - 1);
                U[it] = *(const uint4*)(xab + ((size_t)rc * 128 + cc) * 128 + cbase + grp * 8);
            }
        }
    };

    issue_stage(0);

    for (int chunk = 0; chunk < 4; ++chunk) {
#pragma unroll
        for (int half = 0; half < 2; ++half) {
            const int hf = chunk * 2 + half;
            unsigned* xtb = xt[hf & 1];
            // write prefetched U -> xt[hf&1] (its last readers finished 2 phases ago)
#pragma unroll
            for (int it = 0; it < 2; it++) {
                int task = t + it * 256;
                if (task < 480) {
                    int col = task % 40;
                    int rg = task / 40;
                    int row = rg % 6, grp = rg / 6;
                    int cell = row * 40 + col;
                    xtb[(grp * 4 + 0) * 240 + cell] = U[it].x;
                    xtb[(grp * 4 + 1) * 240 + cell] = U[it].y;
                    xtb[(grp * 4 + 2) * 240 + cell] = U[it].z;
                    xtb[(grp * 4 + 3) * 240 + cell] = U[it].w;
                }
            }
            if (hf < 7) issue_stage(hf + 1);
            barrier_lgkm();  // publish xt[hf&1]; also orders prev-chunk MFMA before sv writes
            // gather from xt[hf&1] -> sv
#pragma unroll
            for (int u = 0; u < 2; u++) {
                if (!prV[u]) continue;
                const float w0 = prW[u][0], w1 = prW[u][1], w2 = prW[u][2], w3 = prW[u][3];
                if (prOK[u]) {
                    const unsigned* xp = xtb + prT0[u];
                    unsigned q[8];
#pragma unroll
                    for (int c2 = 0; c2 < 8; c2++) {
                        unsigned c00 = xp[0], c01 = xp[1];
                        unsigned c10 = xp[40], c11 = xp[41];
                        float2v s = unpk2(c00) * w0 + unpk2(c01) * w1
                                  + unpk2(c10) * w2 + unpk2(c11) * w3;
                        q[c2] = cvtpk(s[0], s[1]);
                        xp += 240;
                    }
                    *(uint4*)(svf + ((size_t)((half * 2 + 0) * 288 + prOff[u]) << 3)) =
                        make_uint4(q[0], q[1], q[2], q[3]);
                    *(uint4*)(svf + ((size_t)((half * 2 + 1) * 288 + prOff[u]) << 3)) =
                        make_uint4(q[4], q[5], q[6], q[7]);
                } else {
                    const int a0 = prA[u][0], a1 = prA[u][1], a2 = prA[u][2], a3 = prA[u][3];
                    const int cch = chunk * 32 + half * 16;
#pragma unroll
                    for (int cg2 = 0; cg2 < 2; cg2++) {
                        unsigned q[4];
#pragma unroll
                        for (int pair = 0; pair < 4; pair++) {
                            int co8 = cch + cg2 * 8 + 2 * pair;
                            unsigned c0 = *(const unsigned*)(xab + (size_t)a0 * 128 + co8);
                            unsigned c1 = *(const unsigned*)(xab + (size_t)a1 * 128 + co8);
                            unsigned c2v = *(const unsigned*)(xab + (size_t)a2 * 128 + co8);
                            unsigned c3 = *(const unsigned*)(xab + (size_t)a3 * 128 + co8);
                            float2v s = unpk2(c0) * w0 + unpk2(c1) * w1
                                      + unpk2(c2v) * w2 + unpk2(c3) * w3;
                            q[pair] = cvtpk(s[0], s[1]);
                        }
                        *(uint4*)(svf + ((size_t)((half * 2 + cg2) * 288 + prOff[u]) << 3)) =
                            make_uint4(q[0], q[1], q[2], q[3]);
                    }
                }
            }
        }
        barrier_lgkm();  // sv complete for this chunk
#pragma unroll
        for (int tap = 0; tap < 9; ++tap) {
            short8v af[2];
#pragma unroll
            for (int c = 0; c < 2; c++) {
                int cot = wid * 2 + c;
                af[c] = *(const short8v*)(wpkO + ((((size_t)cot * 4 + chunk) * 9 + tap) * 64 + lane) * 8);
            }
            short8v bf[2];
#pragma unroll
            for (int ps = 0; ps < 2; ps++)
                bf[ps] = *(const short8v*)&sv[lhi][tap][ps * 16 + llo][0];
#pragma unroll
            for (int c = 0; c < 2; c++)
#pragma unroll
                for (int ps = 0; ps < 2; ps++)
                    acc[c][ps] = MFMA16(af[c], bf[ps], acc[c][ps]);
        }
    }

#pragma unroll
    for (int c = 0; c < 2; c++)
#pragma unroll
        for (int ps = 0; ps < 2; ps++)
#pragma unroll
            for (int reg = 0; reg < 4; reg++) {
                int co = (wid * 2 + c) * 16 + lhi * 4 + reg;
                int px = cb + ps * 16 + llo;
                out[((size_t)b * ldc + ch0 + co) * HW + h * Wd + px] = f2bf(acc[c][ps][reg] + b_org[co]);
            }
}

// ---- out = xa + lrelu(norm(dconv)) * (1 - attn) ; all intermediates bf16 ----
__global__ __launch_bounds__(256) void final2_k(const unsigned short* __restrict__ rawAF,
                                                const unsigned short* __restrict__ xabfG,
                                                const float* __restrict__ mu,
                                                const float* __restrict__ rsig,
                                                float* __restrict__ outp) {
    const int seg = blockIdx.x, h = blockIdx.y, b = blockIdx.z;
    const int t = threadIdx.x;
    __shared__ unsigned short la[64][128];
    {
        const int px = t >> 2, part = t & 3;
        const unsigned short* sp = xabfG + ((size_t)b * HW + h * 128 + seg * 64 + px) * 128 + part * 32;
        uint4* lp = (uint4*)&la[px][part * 32];
        lp[0] = *(const uint4*)sp;
        lp[1] = *(const uint4*)(sp + 8);
        lp[2] = *(const uint4*)(sp + 16);
        lp[3] = *(const uint4*)(sp + 24);
    }
    __syncthreads();
    const int px4 = t & 15, cl = t >> 4;
#pragma unroll
    for (int p = 0; p < 8; p++) {
        int c = p * 16 + cl;
        int plane = b * 128 + c;
        size_t pixo = (size_t)h * Wd + seg * 64 + px4 * 4;
        uint2 av = *(const uint2*)(rawAF + ((size_t)b * 256 + c) * HW + pixo);
        uint2 dv = *(const uint2*)(rawAF + ((size_t)b * 256 + 128 + c) * HW + pixo);
        float2v a01 = unpk2(av.x), a23 = unpk2(av.y);
        float2v d01 = unpk2(dv.x), d23 = unpk2(dv.y);
        float m = mu[plane], rs = rsig[plane];
        float4 o;
        float v;
        v = (d01[0] - m) * rs; v = v > 0.f ? v : 0.2f * v; o.x = bfu(la[px4 * 4 + 0][c]) + v * (1.f - a01[0]);
        v = (d01[1] - m) * rs; v = v > 0.f ? v : 0.2f * v; o.y = bfu(la[px4 * 4 + 1][c]) + v * (1.f - a01[1]);
        v = (d23[0] - m) * rs; v = v > 0.f ? v : 0.2f * v; o.z = bfu(la[px4 * 4 + 2][c]) + v * (1.f - a23[0]);
        v = (d23[1] - m) * rs; v = v > 0.f ? v : 0.2f * v; o.w = bfu(la[px4 * 4 + 3][c]) + v * (1.f - a23[1]);
        *(float4*)(outp + (size_t)plane * HW + pixo) = o;
    }
}

extern "C" void kernel_launch(void* const* d_in, const int* in_sizes, int n_in,
                              void* d_out, int out_size, void* d_ws, size_t ws_size,
                              hipStream_t stream) {
    const float* x      = (const float*)d_in[0];
    const float* w_attn = (const float*)d_in[1];
    const float* b_attn = (const float*)d_in[2];
    const float* w_feat = (const float*)d_in[3];
    const float* b_feat = (const float*)d_in[4];
    const float* w_org  = (const float*)d_in[5];
    const float* b_org  = (const float*)d_in[6];
    const float* w_off  = (const float*)d_in[7];
    const float* b_off  = (const float*)d_in[8];
    const float* w_mask = (const float*)d_in[9];
    const float* b_mask = (const float*)d_in[10];
    float* out = (float*)d_out;
    (void)in_sizes; (void)n_in; (void)out_size; (void)ws_size;

    float* ws = (float*)d_ws;
    unsigned short* rawAF = (unsigned short*)ws;        // bf16 [b][256][HW]; region half-used
    unsigned short* regionA = (unsigned short*)(ws + (size_t)BB * 256 * HW);
    unsigned short* xbfG  = regionA + 16384;             // aliased: x-bf16 then xa-bf16
    const size_t bfElems = (size_t)BB * HW * 128;
    float* offmF = (float*)(regionA + 2 * 16384 + bfElems);
    unsigned short* offm = (unsigned short*)offmF;      // bf16; region half-used
    float* tail = offmF + (size_t)BB * 32 * HW;
    unsigned short* wpkAF = (unsigned short*)tail;
    unsigned short* wpkO  = wpkAF + (size_t)16 * 18432;
    unsigned short* wpkOM = wpkO + (size_t)8 * 18432;
    float* bOM = (float*)(wpkOM + (size_t)2 * 18432);
    float* mu1 = bOM + 32;
    float* rs1 = mu1 + 512;
    float* mu2 = rs1 + 512;
    float* rs2 = mu2 + 512;

    repack_all_k<<<(26 * 18432 + 32 + BDIM - 1) / BDIM, BDIM, 0, stream>>>(
        w_attn, w_feat, w_org, w_off, w_mask, b_off, b_mask, wpkAF, wpkO, wpkOM, bOM);

    tobf_k<<<dim3(Hh, BB), BDIM, 0, stream>>>(x, xbfG);

    conv3_k<4, 2, true><<<1024, BDIM, 0, stream>>>(
        xbfG, wpkAF, b_attn, b_feat, 128, 128, rawAF, 256, 0);

    inorm_stats_k<<<BB * Cc, BDIM, 0, stream>>>(rawAF, mu1, rs1, 256, 128);

    xattned2_k<<<dim3(2, Hh, BB), BDIM, 0, stream>>>(rawAF, mu1, rs1, xbfG);

    conv3_k<2, 1, false><<<256, BDIM, 0, stream>>>(
        xbfG, wpkOM, bOM, bOM, 32, 0, offm, 32, 0);

    deform_mfma_k<<<dim3(4, Hh, BB), BDIM, 0, stream>>>(
        xbfG, offm, wpkO, b_org, rawAF, 256, 128);

    inorm_stats_k<<<BB * Cc, BDIM, 0, stream>>>(rawAF, mu2, rs2, 256, 128);

    final2_k<<<dim3(2, Hh, BB), BDIM, 0, stream>>>(rawAF, xbfG, mu2, rs2, out);
}